// Round 6
// baseline (1654.566 us; speedup 1.0000x reference)
//
#include <hip/hip_runtime.h>
#include <math.h>

// FusionShiftingGraph: two 4-layer no-residual transformer stacks + final LN.
// Round 11: k_attn double-buffered. Round-5 counters: attn = 8x92us (46% of
// runtime), MfmaUtil 12%, VALU 28%, HBM 9% -> latency-bound on the per-tile
// serial {issue 6 async16 -> vmcnt(0) drain -> compute} chain (load latency
// fully exposed every tile, 2 barriers/tile).  Now: stage tile it+1 into
// buf[cur^1] BEFORE computing tile it from buf[cur]; single __syncthreads per
// tile (its vmcnt drain lands after ~1500cy of compute -> nearly free).
// LDS 33.8->58.4KB, still 2 blocks/CU.  GEMMs/embed/conv unchanged (r10).
//
// Segments: [0,50) [50,425) [425,800).  B=8, N=800, D=768, H=8, hd=96.

#define NTOK 800
#define ROWS 6400          // B*N
#define DIM 768
#define QKVD 2304
#define HD 96
#define NTILE 26           // padded key space 832 = 26 x 32
#define BHSTR 79872        // per-bh plane stride (26*384*8 u16)

typedef unsigned short u16;
typedef unsigned int u32;
using bf16x8 = __attribute__((ext_vector_type(8))) short;   // 8 bf16 (4 VGPRs)
using f32x4  = __attribute__((ext_vector_type(4))) float;

__device__ __forceinline__ u16 f2bf(float x) {            // RNE fp32->bf16
  union { float f; u32 u; } v; v.f = x;
  u32 r = v.u + 0x7fffu + ((v.u >> 16) & 1u);
  return (u16)(r >> 16);
}
__device__ __forceinline__ float bf2f(u16 h) {
  union { u32 u; float f; } v; v.u = ((u32)h) << 16;
  return v.f;
}
__device__ __forceinline__ u32 asu(float x) { union { float f; u32 u; } v; v.f = x; return v.u; }
__device__ __forceinline__ float asf(u32 x) { union { u32 u; float f; } v; v.u = x; return v.f; }
__device__ __forceinline__ void async16(const u16* g, u16* l) {
  __builtin_amdgcn_global_load_lds((const __attribute__((address_space(1))) u32*)g,
                                   (__attribute__((address_space(3))) u32*)l,
                                   16, 0, 0);
}
// bijective XCD chunk remap (m204): consecutive new-ids land on one XCD
__device__ __forceinline__ int xcd_swz(int orig, int nblk) {
  int cq = nblk >> 3, cr = nblk & 7;
  int xcd = orig & 7, pos = orig >> 3;
  return (xcd < cr ? xcd * (cq + 1) : cr * (cq + 1) + (xcd - cr) * cq) + pos;
}

// ---------------------------------------------------------------- embed
__global__ __launch_bounds__(256) void k_embed(const float* __restrict__ s0,
                                               const float* __restrict__ s1,
                                               const float* __restrict__ s2,
                                               float* __restrict__ x) {
  int row = blockIdx.x;            // 0..6399
  int b = row / NTOK, n = row % NTOK;
  const float* src; int ln;
  if (n < 50)       { src = s0 + ((size_t)b * 50  + n)         * DIM; ln = n; }
  else if (n < 425) { src = s1 + ((size_t)b * 375 + (n - 50))  * DIM; ln = n - 50; }
  else              { src = s2 + ((size_t)b * 375 + (n - 425)) * DIM; ln = n - 425; }
  float p = (float)(ln + 2);       // fairseq: positions start at padding_idx+1=2
  const float negk = -0.024047108543801f;   // -ln(10000)/383
  float* dst = x + (size_t)row * DIM;
  for (int i = 0; i < 3; i++) {
    int d = threadIdx.x + (i << 8);
    int dd = (d < 384) ? d : d - 384;
    float ang = p * expf((float)dd * negk);
    float pe = (d < 384) ? sinf(ang) : cosf(ang);
    dst[d] = 27.712812921102035f * src[d] + pe;   // sqrt(768)*s + pe
  }
}

// ------------------------------------------------- fp32 -> (hi,lo) bf16 planes
__global__ __launch_bounds__(256) void k_conv(const float* __restrict__ x,
                                              u16* __restrict__ hi,
                                              u16* __restrict__ lo, int n8) {
  int i = blockIdx.x * 256 + threadIdx.x;   // 8 elems / thread
  if (i >= n8) return;
  float4 a = ((const float4*)x)[i * 2];
  float4 b = ((const float4*)x)[i * 2 + 1];
  float v[8] = {a.x, a.y, a.z, a.w, b.x, b.y, b.z, b.w};
  u32 hp[4], lp[4];
#pragma unroll
  for (int j = 0; j < 4; j++) {
    u16 h0 = f2bf(v[2 * j]), h1 = f2bf(v[2 * j + 1]);
    u16 l0 = f2bf(v[2 * j] - bf2f(h0));
    u16 l1 = f2bf(v[2 * j + 1] - bf2f(h1));
    hp[j] = (u32)h0 | ((u32)h1 << 16);
    lp[j] = (u32)l0 | ((u32)l1 << 16);
  }
  ((uint4*)hi)[i] = make_uint4(hp[0], hp[1], hp[2], hp[3]);
  ((uint4*)lo)[i] = make_uint4(lp[0], lp[1], lp[2], lp[3]);
}

// ------------------------------------------- pipelined 128^2 split-bf16 GEMM
// Out-projection. C = A*W^T + bias; optional fp32 store (wantF) and/or 2-plane
// bf16 store (Chi/Clo) feeding the next GEMM's A-operand. 256 threads = 4
// waves (2x2), each owns 64x64 (4x4 16x16 frags, 3 MFMA each for hi/lo
// planes). BK=32, depth-2 LDS (2 x 32KB: Ah|Al|Bh|Bl), pre-swizzled async16
// staging, counted vmcnt(8) (never 0 in-loop), 2 barriers/K-step, quadrants
// LL->LH->HL->HH with read-ahead; next step's (aL,bL) reads overlap HH.
// 64KB LDS -> 2 blocks/CU for inter-block overlap. XCD chunk swizzle.
__global__ __launch_bounds__(256, 2) void k_gemm_out(
    const u16* __restrict__ Ah, const u16* __restrict__ Al,
    const u16* __restrict__ Bh, const u16* __restrict__ Bl,
    const float* __restrict__ bias, float* __restrict__ C,
    u16* __restrict__ Chi, u16* __restrict__ Clo, int wantF,
    int N, int K) {
  __shared__ __align__(16) u16 sm[2 * 16384];   // 64 KB
  int tid = threadIdx.x;
  int wave = tid >> 6, lane = tid & 63;
  int l15 = lane & 15, quad = lane >> 4;
  int wr = wave >> 1, wc = wave & 1;            // 2x2 waves, each 64x64
  int nbx = (int)gridDim.x;
  int nblk = nbx * (int)gridDim.y;
  int orig = (int)blockIdx.y * nbx + (int)blockIdx.x;
  int nid = xcd_swz(orig, nblk);
  int by = nid / nbx, bx = nid - by * nbx;
  int m0 = by << 7, n0 = bx << 7;

  // staging: chunk c = j*256 + tid, j=0..7 -> {Ah,Al,Bh,Bl} x {rows 0-63,64-127}
  int srow = tid >> 2, sp = tid & 3;
  int offE = srow * K + ((sp ^ ((srow >> 1) & 3)) << 3);
  int offO = offE + (K << 6);                   // +64 rows (XOR phase invariant)
  const u16* Agh = Ah + (size_t)m0 * K;
  const u16* Agl = Al + (size_t)m0 * K;
  const u16* Bgh = Bh + (size_t)n0 * K;
  const u16* Bgl = Bl + (size_t)n0 * K;
  u16* lb = &sm[tid * 8];

  f32x4 acc[4][4];
#pragma unroll
  for (int i = 0; i < 4; i++)
#pragma unroll
    for (int j = 0; j < 4; j++) acc[i][j] = (f32x4){0.f, 0.f, 0.f, 0.f};

  int nk = K >> 5;                              // 24 K-steps
  int qoff = (quad ^ ((l15 >> 1) & 3)) << 3;    // frag-read XOR swizzle
  int abase = ((wr << 6) + l15) * 32 + qoff;            // A-frag LDS base
  int bbase = 8192 + ((wc << 6) + l15) * 32 + qoff;     // B-frag LDS base

#define STG(bsel, koff) {                         \
    u16* d_ = lb + ((bsel) << 14);                \
    async16(Agh + offE + (koff), d_);             \
    async16(Agh + offO + (koff), d_ + 2048);      \
    async16(Agl + offE + (koff), d_ + 4096);      \
    async16(Agl + offO + (koff), d_ + 6144);      \
    async16(Bgh + offE + (koff), d_ + 8192);      \
    async16(Bgh + offO + (koff), d_ + 10240);     \
    async16(Bgl + offE + (koff), d_ + 12288);     \
    async16(Bgl + offO + (koff), d_ + 14336); }

  STG(0, 0);
  STG(1, 32);
  asm volatile("s_waitcnt vmcnt(8)" ::: "memory");   // buf0's 8 loads landed
  __builtin_amdgcn_s_barrier();
  asm volatile("" ::: "memory");

  // loop-carried: rows i0-1 (hi/lo), cols j0-1 (hi/lo)
  bf16x8 aLh[2], aLv[2], bLh[2], bLv[2];
  {
    const u16* sa = &sm[abase];
    const u16* sb = &sm[bbase];
#pragma unroll
    for (int i = 0; i < 2; i++) {
      aLh[i] = *(const bf16x8*)(sa + i * 512);
      aLv[i] = *(const bf16x8*)(sa + 4096 + i * 512);
    }
#pragma unroll
    for (int j = 0; j < 2; j++) {
      bLh[j] = *(const bf16x8*)(sb + j * 512);
      bLv[j] = *(const bf16x8*)(sb + 4096 + j * 512);
    }
  }

  for (int t = 0; t < nk; ++t) {
    asm volatile("" ::: "memory");
    int bufo = (t & 1) << 14;
    int nxto = ((t + 1) & 1) << 14;
    const u16* sa = &sm[bufo + abase];
    const u16* sb = &sm[bufo + bbase];
    const u16* na = &sm[nxto + abase];
    const u16* nb = &sm[nxto + bbase];
    bf16x8 aHh[2], aHv[2], bHh[2], bHv[2];

    // ---- LL: read-ahead bH; MFMA (i0-1)x(j0-1)
#pragma unroll
    for (int j = 0; j < 2; j++) {
      bHh[j] = *(const bf16x8*)(sb + (j + 2) * 512);
      bHv[j] = *(const bf16x8*)(sb + 4096 + (j + 2) * 512);
    }
    __builtin_amdgcn_s_setprio(1);
#pragma unroll
    for (int i = 0; i < 2; i++)
#pragma unroll
      for (int j = 0; j < 2; j++) {
        acc[i][j] = __builtin_amdgcn_mfma_f32_16x16x32_bf16(aLh[i], bLh[j], acc[i][j], 0, 0, 0);
        acc[i][j] = __builtin_amdgcn_mfma_f32_16x16x32_bf16(aLh[i], bLv[j], acc[i][j], 0, 0, 0);
        acc[i][j] = __builtin_amdgcn_mfma_f32_16x16x32_bf16(aLv[i], bLh[j], acc[i][j], 0, 0, 0);
      }
    __builtin_amdgcn_s_setprio(0);

    // ---- LH: read-ahead aH; MFMA (i0-1)x(j2-3)
#pragma unroll
    for (int i = 0; i < 2; i++) {
      aHh[i] = *(const bf16x8*)(sa + (i + 2) * 512);
      aHv[i] = *(const bf16x8*)(sa + 4096 + (i + 2) * 512);
    }
    __builtin_amdgcn_s_setprio(1);
#pragma unroll
    for (int i = 0; i < 2; i++)
#pragma unroll
      for (int j = 0; j < 2; j++) {
        acc[i][j + 2] = __builtin_amdgcn_mfma_f32_16x16x32_bf16(aLh[i], bHh[j], acc[i][j + 2], 0, 0, 0);
        acc[i][j + 2] = __builtin_amdgcn_mfma_f32_16x16x32_bf16(aLh[i], bHv[j], acc[i][j + 2], 0, 0, 0);
        acc[i][j + 2] = __builtin_amdgcn_mfma_f32_16x16x32_bf16(aLv[i], bHh[j], acc[i][j + 2], 0, 0, 0);
      }
    __builtin_amdgcn_s_setprio(0);

    // ---- HL: MFMA (i2-3)x(j0-1); bL dead after
    __builtin_amdgcn_s_setprio(1);
#pragma unroll
    for (int i = 0; i < 2; i++)
#pragma unroll
      for (int j = 0; j < 2; j++) {
        acc[i + 2][j] = __builtin_amdgcn_mfma_f32_16x16x32_bf16(aHh[i], bLh[j], acc[i + 2][j], 0, 0, 0);
        acc[i + 2][j] = __builtin_amdgcn_mfma_f32_16x16x32_bf16(aHh[i], bLv[j], acc[i + 2][j], 0, 0, 0);
        acc[i + 2][j] = __builtin_amdgcn_mfma_f32_16x16x32_bf16(aHv[i], bLh[j], acc[i + 2][j], 0, 0, 0);
      }
    __builtin_amdgcn_s_setprio(0);

    // ---- hand-off
    asm volatile("s_waitcnt lgkmcnt(0)" ::: "memory");
    __builtin_amdgcn_s_barrier();              // all waves done reading cur
    asm volatile("" ::: "memory");
    {
      int kn = (t + 2 < nk) ? ((t + 2) << 5) : 0;   // tail: dead re-stage
      STG(t & 1, kn);
    }
    asm volatile("s_waitcnt vmcnt(8)" ::: "memory"); // nxt buffer landed
    __builtin_amdgcn_s_barrier();
    asm volatile("" ::: "memory");

    // ---- boundary reads (nxt aL,bL) overlap the HH MFMA cluster
#pragma unroll
    for (int i = 0; i < 2; i++) {
      aLh[i] = *(const bf16x8*)(na + i * 512);
      aLv[i] = *(const bf16x8*)(na + 4096 + i * 512);
    }
#pragma unroll
    for (int j = 0; j < 2; j++) {
      bLh[j] = *(const bf16x8*)(nb + j * 512);
      bLv[j] = *(const bf16x8*)(nb + 4096 + j * 512);
    }
    // ---- HH: MFMA (i2-3)x(j2-3)
    __builtin_amdgcn_s_setprio(1);
#pragma unroll
    for (int i = 0; i < 2; i++)
#pragma unroll
      for (int j = 0; j < 2; j++) {
        acc[i + 2][j + 2] = __builtin_amdgcn_mfma_f32_16x16x32_bf16(aHh[i], bHh[j], acc[i + 2][j + 2], 0, 0, 0);
        acc[i + 2][j + 2] = __builtin_amdgcn_mfma_f32_16x16x32_bf16(aHh[i], bHv[j], acc[i + 2][j + 2], 0, 0, 0);
        acc[i + 2][j + 2] = __builtin_amdgcn_mfma_f32_16x16x32_bf16(aHv[i], bHh[j], acc[i + 2][j + 2], 0, 0, 0);
      }
    __builtin_amdgcn_s_setprio(0);
  }
#undef STG

  asm volatile("s_waitcnt vmcnt(0)" ::: "memory");   // drain tail stages
  __builtin_amdgcn_s_barrier();

  // ---- epilogue: fp32 + bias and/or RNE 2-plane bf16
#pragma unroll
  for (int i = 0; i < 4; i++) {
    int row0 = m0 + wr * 64 + i * 16 + quad * 4;
#pragma unroll
    for (int j = 0; j < 4; j++) {
      int col = n0 + wc * 64 + j * 16 + l15;
      float bv = bias[col];
#pragma unroll
      for (int r = 0; r < 4; r++) {
        size_t idx = (size_t)(row0 + r) * N + col;
        float v = acc[i][j][r] + bv;
        if (wantF) C[idx] = v;
        if (Chi) {
          u16 hu = f2bf(v);
          Chi[idx] = hu;
          Clo[idx] = f2bf(v - bf2f(hu));
        }
      }
    }
  }
}

// ------------------------------------------- 256x256 pipelined split-bf16 GEMM
// QKV projection. Structure as k_gemm_out but 512 threads = 8 waves (2x4),
// each wave 128x64; BK=32, depth-2 128KB LDS, counted vmcnt(8), quadrants
// LL->LH->HL->HH with read-ahead, 2 barriers/K-step. XCD chunk swizzle.
__global__ __launch_bounds__(512, 2) void k_gemm_qkv(
    const u16* __restrict__ Ah, const u16* __restrict__ Al,
    const u16* __restrict__ Bh, const u16* __restrict__ Bl,
    const float* __restrict__ bias, float* __restrict__ C,
    int N, int K) {
  __shared__ __align__(16) u16 sm[2 * 32768];   // 128 KB
  int tid = threadIdx.x;
  int wave = tid >> 6, lane = tid & 63;
  int l15 = lane & 15, quad = lane >> 4;
  int wr = wave >> 2, wc = wave & 3;            // 2 (row) x 4 (col) waves
  int nbx = (int)gridDim.x;
  int nblk = nbx * (int)gridDim.y;
  int orig = (int)blockIdx.y * nbx + (int)blockIdx.x;
  int nid = xcd_swz(orig, nblk);
  int by = nid / nbx, bx = nid - by * nbx;
  int m0 = by << 8, n0 = bx << 8;

  // per-thread staging geometry: chunk c = j*512 + tid, j = 0..7
  int srow = tid >> 2, sp = tid & 3;
  int offE = srow * K + ((sp ^ ((srow >> 1) & 3)) << 3);
  int offO = offE + (K << 7);                   // +128 rows
  const u16* Agh = Ah + (size_t)m0 * K;
  const u16* Agl = Al + (size_t)m0 * K;
  const u16* Bgh = Bh + (size_t)n0 * K;
  const u16* Bgl = Bl + (size_t)n0 * K;
  u16* lb = &sm[tid * 8];

  f32x4 acc[8][4];
#pragma unroll
  for (int i = 0; i < 8; i++)
#pragma unroll
    for (int j = 0; j < 4; j++) acc[i][j] = (f32x4){0.f, 0.f, 0.f, 0.f};

  int nk = K >> 5;                              // 24 K-steps
  int qoff = (quad ^ ((l15 >> 1) & 3)) << 3;    // frag-read XOR swizzle
  int abase = ((wr << 7) + l15) * 32 + qoff;            // A-frag LDS base
  int bbase = 16384 + ((wc << 6) + l15) * 32 + qoff;    // B-frag LDS base

#define STG(bsel, koff) {                         \
    u16* d_ = lb + ((bsel) << 15);                \
    async16(Agh + offE + (koff), d_);             \
    async16(Agh + offO + (koff), d_ + 4096);      \
    async16(Agl + offE + (koff), d_ + 8192);      \
    async16(Agl + offO + (koff), d_ + 12288);     \
    async16(Bgh + offE + (koff), d_ + 16384);     \
    async16(Bgh + offO + (koff), d_ + 20480);     \
    async16(Bgl + offE + (koff), d_ + 24576);     \
    async16(Bgl + offO + (koff), d_ + 28672); }

  STG(0, 0);
  STG(1, 32);
  asm volatile("s_waitcnt vmcnt(8)" ::: "memory");   // buf0's 8 loads landed
  __builtin_amdgcn_s_barrier();
  asm volatile("" ::: "memory");

  // loop-carried fragment set: rows i0-3 (hi/lo planes), cols j0-1 (hi/lo)
  bf16x8 aLh[4], aLv[4], bLh[2], bLv[2];
  {
    const u16* sa = &sm[abase];
    const u16* sb = &sm[bbase];
#pragma unroll
    for (int i = 0; i < 4; i++) {
      aLh[i] = *(const bf16x8*)(sa + i * 512);
      aLv[i] = *(const bf16x8*)(sa + 8192 + i * 512);
    }
#pragma unroll
    for (int j = 0; j < 2; j++) {
      bLh[j] = *(const bf16x8*)(sb + j * 512);
      bLv[j] = *(const bf16x8*)(sb + 8192 + j * 512);
    }
  }

  for (int t = 0; t < nk; ++t) {
    asm volatile("" ::: "memory");
    int bufo = (t & 1) << 15;
    int nxto = ((t + 1) & 1) << 15;
    const u16* sa = &sm[bufo + abase];
    const u16* sb = &sm[bufo + bbase];
    const u16* na = &sm[nxto + abase];
    const u16* nb = &sm[nxto + bbase];
    bf16x8 aHh[4], aHv[4], bHh[2], bHv[2];

    // ---- LL: read-ahead bH(cur); MFMA acc[i0-3][j0-1] (aL x bL)
#pragma unroll
    for (int j = 0; j < 2; j++) {
      bHh[j] = *(const bf16x8*)(sb + (j + 2) * 512);
      bHv[j] = *(const bf16x8*)(sb + 8192 + (j + 2) * 512);
    }
    __builtin_amdgcn_s_setprio(1);
#pragma unroll
    for (int i = 0; i < 4; i++)
#pragma unroll
      for (int j = 0; j < 2; j++) {
        acc[i][j] = __builtin_amdgcn_mfma_f32_16x16x32_bf16(aLh[i], bLh[j], acc[i][j], 0, 0, 0);
        acc[i][j] = __builtin_amdgcn_mfma_f32_16x16x32_bf16(aLh[i], bLv[j], acc[i][j], 0, 0, 0);
        acc[i][j] = __builtin_amdgcn_mfma_f32_16x16x32_bf16(aLv[i], bLh[j], acc[i][j], 0, 0, 0);
      }
    __builtin_amdgcn_s_setprio(0);

    // ---- LH: read-ahead aH(cur); MFMA acc[i0-3][j2-3] (aL x bH)
#pragma unroll
    for (int i = 0; i < 4; i++) {
      aHh[i] = *(const bf16x8*)(sa + (i + 4) * 512);
      aHv[i] = *(const bf16x8*)(sa + 8192 + (i + 4) * 512);
    }
    __builtin_amdgcn_s_setprio(1);
#pragma unroll
    for (int i = 0; i < 4; i++)
#pragma unroll
      for (int j = 0; j < 2; j++) {
        acc[i][j + 2] = __builtin_amdgcn_mfma_f32_16x16x32_bf16(aLh[i], bHh[j], acc[i][j + 2], 0, 0, 0);
        acc[i][j + 2] = __builtin_amdgcn_mfma_f32_16x16x32_bf16(aLh[i], bHv[j], acc[i][j + 2], 0, 0, 0);
        acc[i][j + 2] = __builtin_amdgcn_mfma_f32_16x16x32_bf16(aLv[i], bHh[j], acc[i][j + 2], 0, 0, 0);
      }
    __builtin_amdgcn_s_setprio(0);

    // ---- HL: MFMA acc[i4-7][j0-1] (aH x bL); bL dead after
    __builtin_amdgcn_s_setprio(1);
#pragma unroll
    for (int i = 0; i < 4; i++)
#pragma unroll
      for (int j = 0; j < 2; j++) {
        acc[i + 4][j] = __builtin_amdgcn_mfma_f32_16x16x32_bf16(aHh[i], bLh[j], acc[i + 4][j], 0, 0, 0);
        acc[i + 4][j] = __builtin_amdgcn_mfma_f32_16x16x32_bf16(aHh[i], bLv[j], acc[i + 4][j], 0, 0, 0);
        acc[i + 4][j] = __builtin_amdgcn_mfma_f32_16x16x32_bf16(aHv[i], bLh[j], acc[i + 4][j], 0, 0, 0);
      }
    __builtin_amdgcn_s_setprio(0);

    // ---- hand-off: all reads of cur drained; overwrite cur; expose nxt
    asm volatile("s_waitcnt lgkmcnt(0)" ::: "memory");
    __builtin_amdgcn_s_barrier();              // all waves done reading cur
    asm volatile("" ::: "memory");
    {
      int kn = (t + 2 < nk) ? ((t + 2) << 5) : 0;   // tail: dead re-stage
      STG(t & 1, kn);
    }
    asm volatile("s_waitcnt vmcnt(8)" ::: "memory"); // nxt buffer's loads landed
    __builtin_amdgcn_s_barrier();              // nxt staged visible block-wide
    asm volatile("" ::: "memory");

    // ---- boundary reads (nxt aL,bL) overlap the HH MFMA cluster
#pragma unroll
    for (int i = 0; i < 4; i++) {
      aLh[i] = *(const bf16x8*)(na + i * 512);
      aLv[i] = *(const bf16x8*)(na + 8192 + i * 512);
    }
#pragma unroll
    for (int j = 0; j < 2; j++) {
      bLh[j] = *(const bf16x8*)(nb + j * 512);
      bLv[j] = *(const bf16x8*)(nb + 8192 + j * 512);
    }
    // ---- HH: MFMA acc[i4-7][j2-3] (aH x bH)
    __builtin_amdgcn_s_setprio(1);
#pragma unroll
    for (int i = 0; i < 4; i++)
#pragma unroll
      for (int j = 0; j < 2; j++) {
        acc[i + 4][j + 2] = __builtin_amdgcn_mfma_f32_16x16x32_bf16(aHh[i], bHh[j], acc[i + 4][j + 2], 0, 0, 0);
        acc[i + 4][j + 2] = __builtin_amdgcn_mfma_f32_16x16x32_bf16(aHh[i], bHv[j], acc[i + 4][j + 2], 0, 0, 0);
        acc[i + 4][j + 2] = __builtin_amdgcn_mfma_f32_16x16x32_bf16(aHv[i], bHh[j], acc[i + 4][j + 2], 0, 0, 0);
      }
    __builtin_amdgcn_s_setprio(0);
  }
#undef STG

  asm volatile("s_waitcnt vmcnt(0)" ::: "memory");   // drain tail stages
  __builtin_amdgcn_s_barrier();

  // ---- epilogue: fp32 + bias
#pragma unroll
  for (int i = 0; i < 8; i++) {
    int row0 = m0 + wr * 128 + i * 16 + quad * 4;
#pragma unroll
    for (int j = 0; j < 4; j++) {
      int col = n0 + wc * 64 + j * 16 + l15;
      float bv = bias[col];
#pragma unroll
      for (int r = 0; r < 4; r++)
        C[(size_t)(row0 + r) * N + col] = acc[i][j][r] + bv;
    }
  }
}

// ------------------------------------------- K/V conversion -> tiled planes
// Kt[bh][tile26][chunk=(df*4+quad)*32+key][8]:  K[n=key'-off][df*32+quad*8+j]
// Vt[bh][tile26][chunk=quad*96+d][8]:           V[key'=tile*32+quad*8+j][d]
// trunc 2-plane bf16, pads zeroed. Grid: 13 (64-key chunks) x 64 bh.
__global__ __launch_bounds__(256) void k_convkv(const float* __restrict__ qkv,
                                                u16* __restrict__ Kthi,
                                                u16* __restrict__ Ktlo,
                                                u16* __restrict__ Vthi,
                                                u16* __restrict__ VtloA,
                                                u16* __restrict__ VtloB) {
  int ck = blockIdx.x >> 6;        // 0..12
  int bh = blockIdx.x & 63;
  int b = bh >> 3, h = bh & 7;
  int kt = ck << 6;
  int ve  = kt < 64 ? 50 : kt < 448 ? 439 : 823;   // valid end (padded coords)
  int off = kt < 64 ? 0  : kt < 448 ? 14  : 23;    // key' - off = real n
  __shared__ float Ls[96 * 68];
  int tid = threadIdx.x;
  size_t base = (size_t)b * NTOK;
  u16* vtlo = (bh < 32) ? (VtloA + (size_t)bh * BHSTR)
                        : (VtloB + (size_t)(bh - 32) * BHSTR);
  u16* kthi = Kthi + (size_t)bh * BHSTR;
  u16* ktlo = Ktlo + (size_t)bh * BHSTR;
  u16* vthi = Vthi + (size_t)bh * BHSTR;

  // ---- K: fragment-order convert
#pragma unroll
  for (int i = 0; i < 3; i++) {
    int c = i * 256 + tid;            // 768 = 64 keys x 12 d-chunks
    int key = c / 12, dc = c - key * 12;
    int kp = kt + key;
    uint4 hi4 = make_uint4(0, 0, 0, 0), lo4 = make_uint4(0, 0, 0, 0);
    if (kp < ve) {
      const float* p = qkv + (base + kp - off) * QKVD + DIM + h * HD + dc * 8;
      float4 a = *(const float4*)p;
      float4 e = *(const float4*)(p + 4);
      float xs[8] = {a.x, a.y, a.z, a.w, e.x, e.y, e.z, e.w};
      u32 hp[4], lp[4];
#pragma unroll
      for (int j = 0; j < 4; j++) {
        u32 b0 = asu(xs[2 * j]), b1 = asu(xs[2 * j + 1]);
        hp[j] = (b0 >> 16) | (b1 & 0xffff0000u);
        float l0 = xs[2 * j] - asf(b0 & 0xffff0000u);
        float l1 = xs[2 * j + 1] - asf(b1 & 0xffff0000u);
        lp[j] = (asu(l0) >> 16) | (asu(l1) & 0xffff0000u);
      }
      hi4 = make_uint4(hp[0], hp[1], hp[2], hp[3]);
      lo4 = make_uint4(lp[0], lp[1], lp[2], lp[3]);
    }
    int tile = (kt >> 5) + (key >> 5), key32 = key & 31;
    size_t go = ((size_t)tile * 384 + dc * 32 + key32) * 8;
    *(uint4*)(kthi + go) = hi4;
    *(uint4*)(ktlo + go) = lo4;
  }

  // ---- V: transpose via LDS, fragment-order emit
#pragma unroll
  for (int i = 0; i < 6; i++) {
    int c = i * 256 + tid;            // 1536 = 64 keys x 24 float4-chunks
    int key = c / 24, fc = c - key * 24;
    int kp = kt + key;
    float4 v = make_float4(0.f, 0.f, 0.f, 0.f);
    if (kp < ve)
      v = *(const float4*)(qkv + (base + kp - off) * QKVD + 2 * DIM + h * HD + fc * 4);
    Ls[(fc * 4 + 0) * 68 + key] = v.x;
    Ls[(fc * 4 + 1) * 68 + key] = v.y;
    Ls[(fc * 4 + 2) * 68 + key] = v.z;
    Ls[(fc * 4 + 3) * 68 + key] = v.w;
  }
  __syncthreads();
#pragma unroll
  for (int i = 0; i < 3; i++) {
    int c = i * 256 + tid;            // 768 = 2 tiles x 384 chunks
    int tl = c / 384, cc = c - tl * 384;
    int quad = cc / 96, d = cc - quad * 96;
    const float* ls = &Ls[d * 68 + tl * 32 + quad * 8];
    u32 hp[4], lp[4];
#pragma unroll
    for (int j = 0; j < 4; j++) {
      float x0v = ls[2 * j], x1v = ls[2 * j + 1];
      u32 b0 = asu(x0v), b1 = asu(x1v);
      hp[j] = (b0 >> 16) | (b1 & 0xffff0000u);
      float l0 = x0v - asf(b0 & 0xffff0000u);
      float l1 = x1v - asf(b1 & 0xffff0000u);
      lp[j] = (asu(l0) >> 16) | (asu(l1) & 0xffff0000u);
    }
    size_t go = ((size_t)((kt >> 5) + tl) * 384 + cc) * 8;
    *(uint4*)(vthi + go) = make_uint4(hp[0], hp[1], hp[2], hp[3]);
    *(uint4*)(vtlo + go) = make_uint4(lp[0], lp[1], lp[2], lp[3]);
  }
}

// ------------------------------------------- MFMA flash attention (r3 shape)
// 13 q-tiles x 64 bh. 64 q-rows/block, 4 waves each own 16 rows. Double-
// buffered K/V staging: stage tile it+1 into buf[cur^1] BEFORE computing
// tile it from buf[cur]; ONE __syncthreads per tile (its implicit vmcnt(0)
// drain lands after the full compute -> load latency hidden). buf[cur^1] is
// safe to overwrite: its last reads were in it-1, sealed by that barrier.
// Output written as RNE 2-plane bf16 A-operand planes (feeds out-proj GEMM).
__global__ __launch_bounds__(256) void k_attn(const float* __restrict__ qkv,
                                              const u16* __restrict__ Kthi,
                                              const u16* __restrict__ Ktlo,
                                              const u16* __restrict__ Vthi,
                                              const u16* __restrict__ VtloA,
                                              const u16* __restrict__ VtloB,
                                              u16* __restrict__ ohi,
                                              u16* __restrict__ olo,
                                              int intra) {
  int t  = blockIdx.x >> 6;        // 0..12
  int bh = blockIdx.x & 63;
  int b = bh >> 3, h = bh & 7;

  int seg, q0, qlen;
  if (t == 0)      { seg = 0; q0 = 0;                  qlen = 50; }
  else if (t <= 6) { seg = 1; q0 = 50 + ((t - 1) << 6);  qlen = (425 - q0 < 64) ? (425 - q0) : 64; }
  else             { seg = 2; q0 = 425 + ((t - 7) << 6); qlen = (800 - q0 < 64) ? (800 - q0) : 64; }

  // key ranges in padded coords
  int r0s, r0e, r1s = 0, r1e = 0;
  if (intra) {
    r0s = (seg == 0) ? 0 : (seg == 1) ? 64 : 448;
    r0e = (seg == 0) ? 64 : (seg == 1) ? 448 : 832;
  } else {
    if (seg == 0)      { r0s = 64; r0e = 832; }
    else if (seg == 1) { r0s = 0;  r0e = 64;  r1s = 448; r1e = 832; }
    else               { r0s = 0;  r0e = 448; }
  }
  int n0t = (r0e - r0s) >> 5, n1t = (r1e - r1s) >> 5, nkt = n0t + n1t;

  __shared__ __align__(16) u16 sKV[2 * 12288];  // 2 x (Khi|Klo|Vhi|Vlo) 48KB
  __shared__ u32 sP[4][16 * 36];                // per-wave P transpose (9KB)

  int tid = threadIdx.x;
  int w = tid >> 6, lane = tid & 63, l15 = lane & 15, quad = lane >> 4;
  size_t base = (size_t)b * NTOK;
  const float sm0 = 0.10206207261596575f;   // 96^-0.5

  // staging source/dest precompute (loop-invariant per thread)
  const u16* sp0 = Kthi + (size_t)bh * BHSTR;
  const u16* sp1 = Ktlo + (size_t)bh * BHSTR;
  const u16* sp2 = Vthi + (size_t)bh * BHSTR;
  const u16* sp3 = (bh < 32) ? (VtloA + (size_t)bh * BHSTR)
                             : (VtloB + (size_t)(bh - 32) * BHSTR);
  const u16* sptr[6];
  u16* dptr[6];
#pragma unroll
  for (int j = 0; j < 6; j++) {
    int c = j * 256 + tid;           // 0..1535
    int rg = c / 384, cc = c - rg * 384;
    const u16* pb = rg == 0 ? sp0 : rg == 1 ? sp1 : rg == 2 ? sp2 : sp3;
    sptr[j] = pb + cc * 8;
    dptr[j] = &sKV[c * 8];
  }

  // ---- Q fragments (RNE 2-plane, pre-scaled) — wave w owns rows w*16..+15
  bf16x8 qh[3], ql[3];
  {
    int q = q0 + w * 16 + l15; if (q > 799) q = 799;
    const float* qp = qkv + (base + q) * QKVD + h * HD;
#pragma unroll
    for (int df = 0; df < 3; df++) {
      float4 x0v = *(const float4*)(qp + df * 32 + quad * 8);
      float4 x1v = *(const float4*)(qp + df * 32 + quad * 8 + 4);
      float xs[8] = {x0v.x, x0v.y, x0v.z, x0v.w, x1v.x, x1v.y, x1v.z, x1v.w};
#pragma unroll
      for (int j = 0; j < 8; j++) {
        float x = xs[j] * sm0;
        u16 hu = f2bf(x);
        u16 lu = f2bf(x - bf2f(hu));
        qh[df][j] = (short)hu; ql[df][j] = (short)lu;
      }
    }
  }

  f32x4 oacc[6];
#pragma unroll
  for (int c = 0; c < 6; c++) oacc[c] = (f32x4){0.f, 0.f, 0.f, 0.f};
  float m_i[4], l_i[4];
#pragma unroll
  for (int r = 0; r < 4; r++) { m_i[r] = -1e30f; l_i[r] = 0.f; }

  u32* sPw = sP[w];

  // ---- prologue: stage tile 0 into buf 0; barrier drains vmcnt
  {
    size_t toff = (size_t)(r0s >> 5) * 3072;
#pragma unroll
    for (int j = 0; j < 6; j++) async16(sptr[j] + toff, dptr[j]);
  }
  __syncthreads();                   // buf0 staged & visible

  for (int it = 0; it < nkt; it++) {
    int kt = (it < n0t) ? (r0s + (it << 5)) : (r1s + ((it - n0t) << 5));
    int ve = kt < 64 ? 50 : kt < 448 ? 439 : 823;
    int cur = it & 1;
    int cbo = cur * 12288;           // current buffer u16 offset

    // ---- stage tile it+1 into buf[cur^1] (safe: last read in it-1, sealed
    //      by that iteration's barrier); latency hides under this compute
    if (it + 1 < nkt) {
      int kn = (it + 1 < n0t) ? (r0s + ((it + 1) << 5))
                              : (r1s + ((it + 1 - n0t) << 5));
      size_t toff = (size_t)(kn >> 5) * 3072;
      int nbo = (cur ^ 1) * 12288;
#pragma unroll
      for (int j = 0; j < 6; j++) async16(sptr[j] + toff, dptr[j] + nbo);
    }

    // ---- S = Q K^T  (K frags: dword bank = 4*l15 mod 32, conflict-free)
    f32x4 Sf[2];
#pragma unroll
    for (int h2 = 0; h2 < 2; h2++) {
      f32x4 s = (f32x4){0.f, 0.f, 0.f, 0.f};
#pragma unroll
      for (int df = 0; df < 3; df++) {
        int co = cbo + ((df * 4 + quad) * 32 + h2 * 16 + l15) * 8;
        bf16x8 kh = *(const bf16x8*)&sKV[co];
        bf16x8 kl = *(const bf16x8*)&sKV[3072 + co];
        s = __builtin_amdgcn_mfma_f32_16x16x32_bf16(qh[df], kh, s, 0, 0, 0);
        s = __builtin_amdgcn_mfma_f32_16x16x32_bf16(ql[df], kh, s, 0, 0, 0);
        s = __builtin_amdgcn_mfma_f32_16x16x32_bf16(qh[df], kl, s, 0, 0, 0);
      }
      Sf[h2] = s;
    }
    if (kt + l15 >= ve)      Sf[0] = (f32x4){-1e30f, -1e30f, -1e30f, -1e30f};
    if (kt + 16 + l15 >= ve) Sf[1] = (f32x4){-1e30f, -1e30f, -1e30f, -1e30f};

    // ---- online softmax
    float mx[4], al[4], ps0[4], ps1[4], rs[4];
#pragma unroll
    for (int r = 0; r < 4; r++) mx[r] = fmaxf(Sf[0][r], Sf[1][r]);
#pragma unroll
    for (int o = 1; o < 16; o <<= 1)
#pragma unroll
      for (int r = 0; r < 4; r++) mx[r] = fmaxf(mx[r], __shfl_xor(mx[r], o, 64));
#pragma unroll
    for (int r = 0; r < 4; r++) {
      float mn = fmaxf(m_i[r], mx[r]);
      al[r] = __expf(m_i[r] - mn);
      m_i[r] = mn;
      ps0[r] = __expf(Sf[0][r] - mn);
      ps1[r] = __expf(Sf[1][r] - mn);
      rs[r] = ps0[r] + ps1[r];
    }
#pragma unroll
    for (int o = 1; o < 16; o <<= 1)
#pragma unroll
      for (int r = 0; r < 4; r++) rs[r] += __shfl_xor(rs[r], o, 64);
#pragma unroll
    for (int r = 0; r < 4; r++) l_i[r] = l_i[r] * al[r] + rs[r];

    // ---- pack P (trunc 2-plane), transpose via per-wave LDS (intra-wave)
#pragma unroll
    for (int r = 0; r < 4; r++) {
      u32 b0 = asu(ps0[r]);
      float lo0 = ps0[r] - asf(b0 & 0xffff0000u);
      sPw[(quad * 4 + r) * 36 + l15] = (b0 >> 16) | (asu(lo0) & 0xffff0000u);
      u32 b1 = asu(ps1[r]);
      float lo1 = ps1[r] - asf(b1 & 0xffff0000u);
      sPw[(quad * 4 + r) * 36 + 16 + l15] = (b1 >> 16) | (asu(lo1) & 0xffff0000u);
    }
    asm volatile("" ::: "memory");   // intra-wave LDS in-order; block reordering
    uint4 t0 = *(const uint4*)&sPw[l15 * 36 + quad * 8];
    uint4 t1 = *(const uint4*)&sPw[l15 * 36 + quad * 8 + 4];
    u32 tt[8] = {t0.x, t0.y, t0.z, t0.w, t1.x, t1.y, t1.z, t1.w};
    bf16x8 ph, pl;
#pragma unroll
    for (int j = 0; j < 8; j++) {
      ph[j] = (short)(tt[j] & 0xffffu);
      pl[j] = (short)(tt[j] >> 16);
    }

    // ---- rescale O, then O += P V (V frags conflict-free)
    f32x4 alv = {al[0], al[1], al[2], al[3]};
#pragma unroll
    for (int c = 0; c < 6; c++) oacc[c] *= alv;
#pragma unroll
    for (int c = 0; c < 6; c++) {
      int co = cbo + (quad * 96 + c * 16 + l15) * 8;
      bf16x8 vh = *(const bf16x8*)&sKV[2 * 3072 + co];
      bf16x8 vl = *(const bf16x8*)&sKV[3 * 3072 + co];
      oacc[c] = __builtin_amdgcn_mfma_f32_16x16x32_bf16(ph, vh, oacc[c], 0, 0, 0);
      oacc[c] = __builtin_amdgcn_mfma_f32_16x16x32_bf16(ph, vl, oacc[c], 0, 0, 0);
      oacc[c] = __builtin_amdgcn_mfma_f32_16x16x32_bf16(pl, vh, oacc[c], 0, 0, 0);
    }

    // ---- single barrier: seals reads of buf[cur] (next iter overwrites it)
    //      and drains the just-issued stage of buf[cur^1] (vmcnt in barrier)
    __syncthreads();
  }

  // ---- epilogue: RNE 2-plane A-operand output
  float inv[4];
#pragma unroll
  for (int r = 0; r < 4; r++) inv[r] = 1.0f / l_i[r];
#pragma unroll
  for (int c = 0; c < 6; c++)
#pragma unroll
    for (int r = 0; r < 4; r++) {
      int rl = w * 16 + quad * 4 + r;
      if (rl < qlen) {
        float v = oacc[c][r] * inv[r];
        size_t idx = (base + q0 + rl) * DIM + h * HD + c * 16 + l15;
        u16 hu = f2bf(v);
        ohi[idx] = hu;
        olo[idx] = f2bf(v - bf2f(hu));
      }
    }
}

// ---------------------------------------------------------------- layernorm
__global__ __launch_bounds__(256) void k_ln(const float* __restrict__ x,
                                            const float* __restrict__ g,
                                            const float* __restrict__ be,
                                            float* __restrict__ outp) {
  int row = blockIdx.x;
  const float* xr = x + (size_t)row * DIM;
  float v[3]; float s = 0.f;
#pragma unroll
  for (int i = 0; i < 3; i++) { v[i] = xr[threadIdx.x + (i << 8)]; s += v[i]; }
#pragma unroll
  for (int off = 1; off < 64; off <<= 1) s += __shfl_xor(s, off, 64);
  __shared__ float red[4];
  int wv = threadIdx.x >> 6;
  if ((threadIdx.x & 63) == 0) red[wv] = s;
  __syncthreads();
  float mu = (red[0] + red[1] + red[2] + red[3]) * (1.0f / 768.0f);
  float sq = 0.f;
#pragma unroll
  for (int i = 0; i < 3; i++) { float d2 = v[i] - mu; sq += d2 * d2; }
#pragma unroll
  for (int off = 1; off < 64; off <<= 1) sq += __shfl_xor(sq, off, 64);
  __syncthreads();
  if ((threadIdx.x & 63) == 0) red[wv] = sq;
  __syncthreads();
  float var = (red[0] + red[1] + red[2] + red[3]) * (1.0f / 768.0f);
  float rstd = rsqrtf(var + 1e-5f);
  float* orow = outp + (size_t)row * DIM;
#pragma unroll
  for (int i = 0; i < 3; i++) {
    int d = threadIdx.x + (i << 8);
    orow[d] = (v[i] - mu) * rstd * g[d] + be[d];
  }
}

// ---------------------------------------------------------------- launch
extern "C" void kernel_launch(void* const* d_in, const int* in_sizes, int n_in,
                              void* d_out, int out_size, void* d_ws, size_t ws_size,
                              hipStream_t stream) {
  (void)in_sizes; (void)n_in; (void)out_size; (void)ws_size;
  const float* seq0 = (const float*)d_in[0];
  const float* seq1 = (const float*)d_in[1];
  const float* seq2 = (const float*)d_in[2];

  const size_t NX   = (size_t)ROWS * DIM;    // 4,915,200
  const size_t NQKV = (size_t)ROWS * QKVD;   // 14,745,600
  const int WIN_N   = QKVD * DIM;            // 1,769,472
  const int WOUT_N  = DIM * DIM;             //   589,824
  const size_t PLN  = (size_t)64 * BHSTR;    // 5,111,808 u16 per plane

  // ws (128.19 MiB): x0 | qkv | att | X | S.  Time-shared overlays per layer:
  //   x0 region (2NX u16): P1 planes (A of QKV gemm) -> Kthi + VtloA (attn)
  //   att region (2NX u16): embed floats (pre-l0) -> P2 planes (attn out = A
  //                         of out-proj gemm)
  //   X region (2NX u16): Ktlo + VtloB (attn); X floats written only at l==3
  //   S region (PLN u16): WP planes (gemms) <-> Vthi (attn)
  float* x0   = (float*)d_ws;
  float* qkvb = x0   + NX;
  float* att  = qkvb + NQKV;
  float* X    = att  + NX;
  u16*   S    = (u16*)(X + NX);
  u16*   WPh  = S;            u16* WPl  = S + WIN_N;
  u16*   Vthi = S;
  u16*   P1h  = (u16*)x0;     u16* P1l  = P1h + NX;
  u16*   P2h  = (u16*)att;    u16* P2l  = P2h + NX;
  u16*   Kthi = (u16*)x0;     u16* VtloA = Kthi + PLN;   // 32 bh
  u16*   Ktlo = (u16*)X;      u16* VtloB = Ktlo + PLN;   // 32 bh

  for (int g = 0; g < 2; g++) {           // g=0: inter, g=1: intra
    const float* w_in  = (const float*)d_in[3 + 6 * g];
    const float* b_in  = (const float*)d_in[4 + 6 * g];
    const float* w_out = (const float*)d_in[5 + 6 * g];
    const float* b_out = (const float*)d_in[6 + 6 * g];
    const float* ln_g  = (const float*)d_in[7 + 6 * g];
    const float* ln_b  = (const float*)d_in[8 + 6 * g];

    k_embed<<<ROWS, 256, 0, stream>>>(seq0, seq1, seq2, att);

    for (int l = 0; l < 4; l++) {
      if (l == 0)
        k_conv<<<(int)(NX / 8 / 256), 256, 0, stream>>>(att, P1h, P1l, (int)(NX / 8));
      k_conv<<<WIN_N / 8 / 256, 256, 0, stream>>>(
          w_in + (size_t)l * WIN_N, WPh, WPl, WIN_N / 8);
      k_gemm_qkv<<<dim3(QKVD / 256, ROWS / 256), 512, 0, stream>>>(
          P1h, P1l, WPh, WPl, b_in + (size_t)l * QKVD, qkvb, QKVD, DIM);

      k_convkv<<<13 * 64, 256, 0, stream>>>(qkvb, Kthi, Ktlo, Vthi, VtloA, VtloB);
      k_attn<<<13 * 64, 256, 0, stream>>>(qkvb, Kthi, Ktlo, Vthi, VtloA, VtloB,
                                          P2h, P2l, g);

      k_conv<<<WOUT_N / 8 / 256, 256, 0, stream>>>(
          w_out + (size_t)l * WOUT_N, WPh, WPl, WOUT_N / 8);
      k_gemm_out<<<dim3(DIM / 128, ROWS / 128), 256, 0, stream>>>(
          P2h, P2l, WPh, WPl, b_out + (size_t)l * DIM, X,
          P1h, P1l, (l == 3) ? 1 : 0, DIM, DIM);
    }
    k_ln<<<ROWS, 256, 0, stream>>>(X, ln_g, ln_b,
                                   (float*)d_out + (size_t)g * ROWS * DIM);
  }
}

// Round 7
// 1646.711 us; speedup vs baseline: 1.0048x; 1.0048x over previous
//
#include <hip/hip_runtime.h>
#include <math.h>

// FusionShiftingGraph: two 4-layer no-residual transformer stacks + final LN.
// Round 12: k_attn restructured for per-tile overhead amortization. Round-6
// showed dbuf alone ~nil (88.5us, MfmaUtil 12.7) -> cost is the per-tile
// serial softmax chain + barriers, not staging BW.  Now: 7 q-tiles x 128
// rows (4 waves x 2 row-frags of 16), so each 32-key tile's 12 K-ds_reads
// and 12 V-ds_reads feed 72 MFMAs (was 36), softmax reductions for 8 rows
// run in parallel, grid 832->448 blocks.  Prefetch issued strictly AFTER all
// current-tile LDS reads (K, sP, V) so any compiler-inserted vmcnt drain
// lands behind the PV MFMA cluster + barrier.  Math order per row identical
// to r11 -> bitwise-identical output.  GEMMs/embed/conv unchanged.
//
// Segments: [0,50) [50,425) [425,800).  B=8, N=800, D=768, H=8, hd=96.

#define NTOK 800
#define ROWS 6400          // B*N
#define DIM 768
#define QKVD 2304
#define HD 96
#define NTILE 26           // padded key space 832 = 26 x 32
#define BHSTR 79872        // per-bh plane stride (26*384*8 u16)

typedef unsigned short u16;
typedef unsigned int u32;
using bf16x8 = __attribute__((ext_vector_type(8))) short;   // 8 bf16 (4 VGPRs)
using f32x4  = __attribute__((ext_vector_type(4))) float;

__device__ __forceinline__ u16 f2bf(float x) {            // RNE fp32->bf16
  union { float f; u32 u; } v; v.f = x;
  u32 r = v.u + 0x7fffu + ((v.u >> 16) & 1u);
  return (u16)(r >> 16);
}
__device__ __forceinline__ float bf2f(u16 h) {
  union { u32 u; float f; } v; v.u = ((u32)h) << 16;
  return v.f;
}
__device__ __forceinline__ u32 asu(float x) { union { float f; u32 u; } v; v.f = x; return v.u; }
__device__ __forceinline__ float asf(u32 x) { union { u32 u; float f; } v; v.u = x; return v.f; }
__device__ __forceinline__ void async16(const u16* g, u16* l) {
  __builtin_amdgcn_global_load_lds((const __attribute__((address_space(1))) u32*)g,
                                   (__attribute__((address_space(3))) u32*)l,
                                   16, 0, 0);
}
// bijective XCD chunk remap (m204): consecutive new-ids land on one XCD
__device__ __forceinline__ int xcd_swz(int orig, int nblk) {
  int cq = nblk >> 3, cr = nblk & 7;
  int xcd = orig & 7, pos = orig >> 3;
  return (xcd < cr ? xcd * (cq + 1) : cr * (cq + 1) + (xcd - cr) * cq) + pos;
}

// ---------------------------------------------------------------- embed
__global__ __launch_bounds__(256) void k_embed(const float* __restrict__ s0,
                                               const float* __restrict__ s1,
                                               const float* __restrict__ s2,
                                               float* __restrict__ x) {
  int row = blockIdx.x;            // 0..6399
  int b = row / NTOK, n = row % NTOK;
  const float* src; int ln;
  if (n < 50)       { src = s0 + ((size_t)b * 50  + n)         * DIM; ln = n; }
  else if (n < 425) { src = s1 + ((size_t)b * 375 + (n - 50))  * DIM; ln = n - 50; }
  else              { src = s2 + ((size_t)b * 375 + (n - 425)) * DIM; ln = n - 425; }
  float p = (float)(ln + 2);       // fairseq: positions start at padding_idx+1=2
  const float negk = -0.024047108543801f;   // -ln(10000)/383
  float* dst = x + (size_t)row * DIM;
  for (int i = 0; i < 3; i++) {
    int d = threadIdx.x + (i << 8);
    int dd = (d < 384) ? d : d - 384;
    float ang = p * expf((float)dd * negk);
    float pe = (d < 384) ? sinf(ang) : cosf(ang);
    dst[d] = 27.712812921102035f * src[d] + pe;   // sqrt(768)*s + pe
  }
}

// ------------------------------------------------- fp32 -> (hi,lo) bf16 planes
__global__ __launch_bounds__(256) void k_conv(const float* __restrict__ x,
                                              u16* __restrict__ hi,
                                              u16* __restrict__ lo, int n8) {
  int i = blockIdx.x * 256 + threadIdx.x;   // 8 elems / thread
  if (i >= n8) return;
  float4 a = ((const float4*)x)[i * 2];
  float4 b = ((const float4*)x)[i * 2 + 1];
  float v[8] = {a.x, a.y, a.z, a.w, b.x, b.y, b.z, b.w};
  u32 hp[4], lp[4];
#pragma unroll
  for (int j = 0; j < 4; j++) {
    u16 h0 = f2bf(v[2 * j]), h1 = f2bf(v[2 * j + 1]);
    u16 l0 = f2bf(v[2 * j] - bf2f(h0));
    u16 l1 = f2bf(v[2 * j + 1] - bf2f(h1));
    hp[j] = (u32)h0 | ((u32)h1 << 16);
    lp[j] = (u32)l0 | ((u32)l1 << 16);
  }
  ((uint4*)hi)[i] = make_uint4(hp[0], hp[1], hp[2], hp[3]);
  ((uint4*)lo)[i] = make_uint4(lp[0], lp[1], lp[2], lp[3]);
}

// ------------------------------------------- pipelined 128^2 split-bf16 GEMM
// Out-projection. C = A*W^T + bias; optional fp32 store (wantF) and/or 2-plane
// bf16 store (Chi/Clo) feeding the next GEMM's A-operand. 256 threads = 4
// waves (2x2), each owns 64x64 (4x4 16x16 frags, 3 MFMA each for hi/lo
// planes). BK=32, depth-2 LDS (2 x 32KB: Ah|Al|Bh|Bl), pre-swizzled async16
// staging, counted vmcnt(8) (never 0 in-loop), 2 barriers/K-step, quadrants
// LL->LH->HL->HH with read-ahead; next step's (aL,bL) reads overlap HH.
// 64KB LDS -> 2 blocks/CU for inter-block overlap. XCD chunk swizzle.
__global__ __launch_bounds__(256, 2) void k_gemm_out(
    const u16* __restrict__ Ah, const u16* __restrict__ Al,
    const u16* __restrict__ Bh, const u16* __restrict__ Bl,
    const float* __restrict__ bias, float* __restrict__ C,
    u16* __restrict__ Chi, u16* __restrict__ Clo, int wantF,
    int N, int K) {
  __shared__ __align__(16) u16 sm[2 * 16384];   // 64 KB
  int tid = threadIdx.x;
  int wave = tid >> 6, lane = tid & 63;
  int l15 = lane & 15, quad = lane >> 4;
  int wr = wave >> 1, wc = wave & 1;            // 2x2 waves, each 64x64
  int nbx = (int)gridDim.x;
  int nblk = nbx * (int)gridDim.y;
  int orig = (int)blockIdx.y * nbx + (int)blockIdx.x;
  int nid = xcd_swz(orig, nblk);
  int by = nid / nbx, bx = nid - by * nbx;
  int m0 = by << 7, n0 = bx << 7;

  // staging: chunk c = j*256 + tid, j=0..7 -> {Ah,Al,Bh,Bl} x {rows 0-63,64-127}
  int srow = tid >> 2, sp = tid & 3;
  int offE = srow * K + ((sp ^ ((srow >> 1) & 3)) << 3);
  int offO = offE + (K << 6);                   // +64 rows (XOR phase invariant)
  const u16* Agh = Ah + (size_t)m0 * K;
  const u16* Agl = Al + (size_t)m0 * K;
  const u16* Bgh = Bh + (size_t)n0 * K;
  const u16* Bgl = Bl + (size_t)n0 * K;
  u16* lb = &sm[tid * 8];

  f32x4 acc[4][4];
#pragma unroll
  for (int i = 0; i < 4; i++)
#pragma unroll
    for (int j = 0; j < 4; j++) acc[i][j] = (f32x4){0.f, 0.f, 0.f, 0.f};

  int nk = K >> 5;                              // 24 K-steps
  int qoff = (quad ^ ((l15 >> 1) & 3)) << 3;    // frag-read XOR swizzle
  int abase = ((wr << 6) + l15) * 32 + qoff;            // A-frag LDS base
  int bbase = 8192 + ((wc << 6) + l15) * 32 + qoff;     // B-frag LDS base

#define STG(bsel, koff) {                         \
    u16* d_ = lb + ((bsel) << 14);                \
    async16(Agh + offE + (koff), d_);             \
    async16(Agh + offO + (koff), d_ + 2048);      \
    async16(Agl + offE + (koff), d_ + 4096);      \
    async16(Agl + offO + (koff), d_ + 6144);      \
    async16(Bgh + offE + (koff), d_ + 8192);      \
    async16(Bgh + offO + (koff), d_ + 10240);     \
    async16(Bgl + offE + (koff), d_ + 12288);     \
    async16(Bgl + offO + (koff), d_ + 14336); }

  STG(0, 0);
  STG(1, 32);
  asm volatile("s_waitcnt vmcnt(8)" ::: "memory");   // buf0's 8 loads landed
  __builtin_amdgcn_s_barrier();
  asm volatile("" ::: "memory");

  // loop-carried: rows i0-1 (hi/lo), cols j0-1 (hi/lo)
  bf16x8 aLh[2], aLv[2], bLh[2], bLv[2];
  {
    const u16* sa = &sm[abase];
    const u16* sb = &sm[bbase];
#pragma unroll
    for (int i = 0; i < 2; i++) {
      aLh[i] = *(const bf16x8*)(sa + i * 512);
      aLv[i] = *(const bf16x8*)(sa + 4096 + i * 512);
    }
#pragma unroll
    for (int j = 0; j < 2; j++) {
      bLh[j] = *(const bf16x8*)(sb + j * 512);
      bLv[j] = *(const bf16x8*)(sb + 4096 + j * 512);
    }
  }

  for (int t = 0; t < nk; ++t) {
    asm volatile("" ::: "memory");
    int bufo = (t & 1) << 14;
    int nxto = ((t + 1) & 1) << 14;
    const u16* sa = &sm[bufo + abase];
    const u16* sb = &sm[bufo + bbase];
    const u16* na = &sm[nxto + abase];
    const u16* nb = &sm[nxto + bbase];
    bf16x8 aHh[2], aHv[2], bHh[2], bHv[2];

    // ---- LL: read-ahead bH; MFMA (i0-1)x(j0-1)
#pragma unroll
    for (int j = 0; j < 2; j++) {
      bHh[j] = *(const bf16x8*)(sb + (j + 2) * 512);
      bHv[j] = *(const bf16x8*)(sb + 4096 + (j + 2) * 512);
    }
    __builtin_amdgcn_s_setprio(1);
#pragma unroll
    for (int i = 0; i < 2; i++)
#pragma unroll
      for (int j = 0; j < 2; j++) {
        acc[i][j] = __builtin_amdgcn_mfma_f32_16x16x32_bf16(aLh[i], bLh[j], acc[i][j], 0, 0, 0);
        acc[i][j] = __builtin_amdgcn_mfma_f32_16x16x32_bf16(aLh[i], bLv[j], acc[i][j], 0, 0, 0);
        acc[i][j] = __builtin_amdgcn_mfma_f32_16x16x32_bf16(aLv[i], bLh[j], acc[i][j], 0, 0, 0);
      }
    __builtin_amdgcn_s_setprio(0);

    // ---- LH: read-ahead aH; MFMA (i0-1)x(j2-3)
#pragma unroll
    for (int i = 0; i < 2; i++) {
      aHh[i] = *(const bf16x8*)(sa + (i + 2) * 512);
      aHv[i] = *(const bf16x8*)(sa + 4096 + (i + 2) * 512);
    }
    __builtin_amdgcn_s_setprio(1);
#pragma unroll
    for (int i = 0; i < 2; i++)
#pragma unroll
      for (int j = 0; j < 2; j++) {
        acc[i][j + 2] = __builtin_amdgcn_mfma_f32_16x16x32_bf16(aLh[i], bHh[j], acc[i][j + 2], 0, 0, 0);
        acc[i][j + 2] = __builtin_amdgcn_mfma_f32_16x16x32_bf16(aLh[i], bHv[j], acc[i][j + 2], 0, 0, 0);
        acc[i][j + 2] = __builtin_amdgcn_mfma_f32_16x16x32_bf16(aLv[i], bHh[j], acc[i][j + 2], 0, 0, 0);
      }
    __builtin_amdgcn_s_setprio(0);

    // ---- HL: MFMA (i2-3)x(j0-1); bL dead after
    __builtin_amdgcn_s_setprio(1);
#pragma unroll
    for (int i = 0; i < 2; i++)
#pragma unroll
      for (int j = 0; j < 2; j++) {
        acc[i + 2][j] = __builtin_amdgcn_mfma_f32_16x16x32_bf16(aHh[i], bLh[j], acc[i + 2][j], 0, 0, 0);
        acc[i + 2][j] = __builtin_amdgcn_mfma_f32_16x16x32_bf16(aHh[i], bLv[j], acc[i + 2][j], 0, 0, 0);
        acc[i + 2][j] = __builtin_amdgcn_mfma_f32_16x16x32_bf16(aHv[i], bLh[j], acc[i + 2][j], 0, 0, 0);
      }
    __builtin_amdgcn_s_setprio(0);

    // ---- hand-off
    asm volatile("s_waitcnt lgkmcnt(0)" ::: "memory");
    __builtin_amdgcn_s_barrier();              // all waves done reading cur
    asm volatile("" ::: "memory");
    {
      int kn = (t + 2 < nk) ? ((t + 2) << 5) : 0;   // tail: dead re-stage
      STG(t & 1, kn);
    }
    asm volatile("s_waitcnt vmcnt(8)" ::: "memory"); // nxt buffer landed
    __builtin_amdgcn_s_barrier();
    asm volatile("" ::: "memory");

    // ---- boundary reads (nxt aL,bL) overlap the HH MFMA cluster
#pragma unroll
    for (int i = 0; i < 2; i++) {
      aLh[i] = *(const bf16x8*)(na + i * 512);
      aLv[i] = *(const bf16x8*)(na + 4096 + i * 512);
    }
#pragma unroll
    for (int j = 0; j < 2; j++) {
      bLh[j] = *(const bf16x8*)(nb + j * 512);
      bLv[j] = *(const bf16x8*)(nb + 4096 + j * 512);
    }
    // ---- HH: MFMA (i2-3)x(j2-3)
    __builtin_amdgcn_s_setprio(1);
#pragma unroll
    for (int i = 0; i < 2; i++)
#pragma unroll
      for (int j = 0; j < 2; j++) {
        acc[i + 2][j + 2] = __builtin_amdgcn_mfma_f32_16x16x32_bf16(aHh[i], bHh[j], acc[i + 2][j + 2], 0, 0, 0);
        acc[i + 2][j + 2] = __builtin_amdgcn_mfma_f32_16x16x32_bf16(aHh[i], bHv[j], acc[i + 2][j + 2], 0, 0, 0);
        acc[i + 2][j + 2] = __builtin_amdgcn_mfma_f32_16x16x32_bf16(aHv[i], bHh[j], acc[i + 2][j + 2], 0, 0, 0);
      }
    __builtin_amdgcn_s_setprio(0);
  }
#undef STG

  asm volatile("s_waitcnt vmcnt(0)" ::: "memory");   // drain tail stages
  __builtin_amdgcn_s_barrier();

  // ---- epilogue: fp32 + bias and/or RNE 2-plane bf16
#pragma unroll
  for (int i = 0; i < 4; i++) {
    int row0 = m0 + wr * 64 + i * 16 + quad * 4;
#pragma unroll
    for (int j = 0; j < 4; j++) {
      int col = n0 + wc * 64 + j * 16 + l15;
      float bv = bias[col];
#pragma unroll
      for (int r = 0; r < 4; r++) {
        size_t idx = (size_t)(row0 + r) * N + col;
        float v = acc[i][j][r] + bv;
        if (wantF) C[idx] = v;
        if (Chi) {
          u16 hu = f2bf(v);
          Chi[idx] = hu;
          Clo[idx] = f2bf(v - bf2f(hu));
        }
      }
    }
  }
}

// ------------------------------------------- 256x256 pipelined split-bf16 GEMM
// QKV projection. Structure as k_gemm_out but 512 threads = 8 waves (2x4),
// each wave 128x64; BK=32, depth-2 128KB LDS, counted vmcnt(8), quadrants
// LL->LH->HL->HH with read-ahead, 2 barriers/K-step. XCD chunk swizzle.
__global__ __launch_bounds__(512, 2) void k_gemm_qkv(
    const u16* __restrict__ Ah, const u16* __restrict__ Al,
    const u16* __restrict__ Bh, const u16* __restrict__ Bl,
    const float* __restrict__ bias, float* __restrict__ C,
    int N, int K) {
  __shared__ __align__(16) u16 sm[2 * 32768];   // 128 KB
  int tid = threadIdx.x;
  int wave = tid >> 6, lane = tid & 63;
  int l15 = lane & 15, quad = lane >> 4;
  int wr = wave >> 2, wc = wave & 3;            // 2 (row) x 4 (col) waves
  int nbx = (int)gridDim.x;
  int nblk = nbx * (int)gridDim.y;
  int orig = (int)blockIdx.y * nbx + (int)blockIdx.x;
  int nid = xcd_swz(orig, nblk);
  int by = nid / nbx, bx = nid - by * nbx;
  int m0 = by << 8, n0 = bx << 8;

  // per-thread staging geometry: chunk c = j*512 + tid, j = 0..7
  int srow = tid >> 2, sp = tid & 3;
  int offE = srow * K + ((sp ^ ((srow >> 1) & 3)) << 3);
  int offO = offE + (K << 7);                   // +128 rows
  const u16* Agh = Ah + (size_t)m0 * K;
  const u16* Agl = Al + (size_t)m0 * K;
  const u16* Bgh = Bh + (size_t)n0 * K;
  const u16* Bgl = Bl + (size_t)n0 * K;
  u16* lb = &sm[tid * 8];

  f32x4 acc[8][4];
#pragma unroll
  for (int i = 0; i < 8; i++)
#pragma unroll
    for (int j = 0; j < 4; j++) acc[i][j] = (f32x4){0.f, 0.f, 0.f, 0.f};

  int nk = K >> 5;                              // 24 K-steps
  int qoff = (quad ^ ((l15 >> 1) & 3)) << 3;    // frag-read XOR swizzle
  int abase = ((wr << 7) + l15) * 32 + qoff;            // A-frag LDS base
  int bbase = 16384 + ((wc << 6) + l15) * 32 + qoff;    // B-frag LDS base

#define STG(bsel, koff) {                         \
    u16* d_ = lb + ((bsel) << 15);                \
    async16(Agh + offE + (koff), d_);             \
    async16(Agh + offO + (koff), d_ + 4096);      \
    async16(Agl + offE + (koff), d_ + 8192);      \
    async16(Agl + offO + (koff), d_ + 12288);     \
    async16(Bgh + offE + (koff), d_ + 16384);     \
    async16(Bgh + offO + (koff), d_ + 20480);     \
    async16(Bgl + offE + (koff), d_ + 24576);     \
    async16(Bgl + offO + (koff), d_ + 28672); }

  STG(0, 0);
  STG(1, 32);
  asm volatile("s_waitcnt vmcnt(8)" ::: "memory");   // buf0's 8 loads landed
  __builtin_amdgcn_s_barrier();
  asm volatile("" ::: "memory");

  // loop-carried fragment set: rows i0-3 (hi/lo planes), cols j0-1 (hi/lo)
  bf16x8 aLh[4], aLv[4], bLh[2], bLv[2];
  {
    const u16* sa = &sm[abase];
    const u16* sb = &sm[bbase];
#pragma unroll
    for (int i = 0; i < 4; i++) {
      aLh[i] = *(const bf16x8*)(sa + i * 512);
      aLv[i] = *(const bf16x8*)(sa + 8192 + i * 512);
    }
#pragma unroll
    for (int j = 0; j < 2; j++) {
      bLh[j] = *(const bf16x8*)(sb + j * 512);
      bLv[j] = *(const bf16x8*)(sb + 8192 + j * 512);
    }
  }

  for (int t = 0; t < nk; ++t) {
    asm volatile("" ::: "memory");
    int bufo = (t & 1) << 15;
    int nxto = ((t + 1) & 1) << 15;
    const u16* sa = &sm[bufo + abase];
    const u16* sb = &sm[bufo + bbase];
    const u16* na = &sm[nxto + abase];
    const u16* nb = &sm[nxto + bbase];
    bf16x8 aHh[4], aHv[4], bHh[2], bHv[2];

    // ---- LL: read-ahead bH(cur); MFMA acc[i0-3][j0-1] (aL x bL)
#pragma unroll
    for (int j = 0; j < 2; j++) {
      bHh[j] = *(const bf16x8*)(sb + (j + 2) * 512);
      bHv[j] = *(const bf16x8*)(sb + 8192 + (j + 2) * 512);
    }
    __builtin_amdgcn_s_setprio(1);
#pragma unroll
    for (int i = 0; i < 4; i++)
#pragma unroll
      for (int j = 0; j < 2; j++) {
        acc[i][j] = __builtin_amdgcn_mfma_f32_16x16x32_bf16(aLh[i], bLh[j], acc[i][j], 0, 0, 0);
        acc[i][j] = __builtin_amdgcn_mfma_f32_16x16x32_bf16(aLh[i], bLv[j], acc[i][j], 0, 0, 0);
        acc[i][j] = __builtin_amdgcn_mfma_f32_16x16x32_bf16(aLv[i], bLh[j], acc[i][j], 0, 0, 0);
      }
    __builtin_amdgcn_s_setprio(0);

    // ---- LH: read-ahead aH(cur); MFMA acc[i0-3][j2-3] (aL x bH)
#pragma unroll
    for (int i = 0; i < 4; i++) {
      aHh[i] = *(const bf16x8*)(sa + (i + 4) * 512);
      aHv[i] = *(const bf16x8*)(sa + 8192 + (i + 4) * 512);
    }
    __builtin_amdgcn_s_setprio(1);
#pragma unroll
    for (int i = 0; i < 4; i++)
#pragma unroll
      for (int j = 0; j < 2; j++) {
        acc[i][j + 2] = __builtin_amdgcn_mfma_f32_16x16x32_bf16(aLh[i], bHh[j], acc[i][j + 2], 0, 0, 0);
        acc[i][j + 2] = __builtin_amdgcn_mfma_f32_16x16x32_bf16(aLh[i], bHv[j], acc[i][j + 2], 0, 0, 0);
        acc[i][j + 2] = __builtin_amdgcn_mfma_f32_16x16x32_bf16(aLv[i], bHh[j], acc[i][j + 2], 0, 0, 0);
      }
    __builtin_amdgcn_s_setprio(0);

    // ---- HL: MFMA acc[i4-7][j0-1] (aH x bL); bL dead after
    __builtin_amdgcn_s_setprio(1);
#pragma unroll
    for (int i = 0; i < 4; i++)
#pragma unroll
      for (int j = 0; j < 2; j++) {
        acc[i + 4][j] = __builtin_amdgcn_mfma_f32_16x16x32_bf16(aHh[i], bLh[j], acc[i + 4][j], 0, 0, 0);
        acc[i + 4][j] = __builtin_amdgcn_mfma_f32_16x16x32_bf16(aHh[i], bLv[j], acc[i + 4][j], 0, 0, 0);
        acc[i + 4][j] = __builtin_amdgcn_mfma_f32_16x16x32_bf16(aHv[i], bLh[j], acc[i + 4][j], 0, 0, 0);
      }
    __builtin_amdgcn_s_setprio(0);

    // ---- hand-off: all reads of cur drained; overwrite cur; expose nxt
    asm volatile("s_waitcnt lgkmcnt(0)" ::: "memory");
    __builtin_amdgcn_s_barrier();              // all waves done reading cur
    asm volatile("" ::: "memory");
    {
      int kn = (t + 2 < nk) ? ((t + 2) << 5) : 0;   // tail: dead re-stage
      STG(t & 1, kn);
    }
    asm volatile("s_waitcnt vmcnt(8)" ::: "memory"); // nxt buffer's loads landed
    __builtin_amdgcn_s_barrier();              // nxt staged visible block-wide
    asm volatile("" ::: "memory");

    // ---- boundary reads (nxt aL,bL) overlap the HH MFMA cluster
#pragma unroll
    for (int i = 0; i < 4; i++) {
      aLh[i] = *(const bf16x8*)(na + i * 512);
      aLv[i] = *(const bf16x8*)(na + 8192 + i * 512);
    }
#pragma unroll
    for (int j = 0; j < 2; j++) {
      bLh[j] = *(const bf16x8*)(nb + j * 512);
      bLv[j] = *(const bf16x8*)(nb + 8192 + j * 512);
    }
    // ---- HH: MFMA acc[i4-7][j2-3] (aH x bH)
    __builtin_amdgcn_s_setprio(1);
#pragma unroll
    for (int i = 0; i < 4; i++)
#pragma unroll
      for (int j = 0; j < 2; j++) {
        acc[i + 4][j + 2] = __builtin_amdgcn_mfma_f32_16x16x32_bf16(aHh[i], bHh[j], acc[i + 4][j + 2], 0, 0, 0);
        acc[i + 4][j + 2] = __builtin_amdgcn_mfma_f32_16x16x32_bf16(aHh[i], bHv[j], acc[i + 4][j + 2], 0, 0, 0);
        acc[i + 4][j + 2] = __builtin_amdgcn_mfma_f32_16x16x32_bf16(aHv[i], bHh[j], acc[i + 4][j + 2], 0, 0, 0);
      }
    __builtin_amdgcn_s_setprio(0);
  }
#undef STG

  asm volatile("s_waitcnt vmcnt(0)" ::: "memory");   // drain tail stages
  __builtin_amdgcn_s_barrier();

  // ---- epilogue: fp32 + bias
#pragma unroll
  for (int i = 0; i < 8; i++) {
    int row0 = m0 + wr * 128 + i * 16 + quad * 4;
#pragma unroll
    for (int j = 0; j < 4; j++) {
      int col = n0 + wc * 64 + j * 16 + l15;
      float bv = bias[col];
#pragma unroll
      for (int r = 0; r < 4; r++)
        C[(size_t)(row0 + r) * N + col] = acc[i][j][r] + bv;
    }
  }
}

// ------------------------------------------- K/V conversion -> tiled planes
// Kt[bh][tile26][chunk=(df*4+quad)*32+key][8]:  K[n=key'-off][df*32+quad*8+j]
// Vt[bh][tile26][chunk=quad*96+d][8]:           V[key'=tile*32+quad*8+j][d]
// trunc 2-plane bf16, pads zeroed. Grid: 13 (64-key chunks) x 64 bh.
__global__ __launch_bounds__(256) void k_convkv(const float* __restrict__ qkv,
                                                u16* __restrict__ Kthi,
                                                u16* __restrict__ Ktlo,
                                                u16* __restrict__ Vthi,
                                                u16* __restrict__ VtloA,
                                                u16* __restrict__ VtloB) {
  int ck = blockIdx.x >> 6;        // 0..12
  int bh = blockIdx.x & 63;
  int b = bh >> 3, h = bh & 7;
  int kt = ck << 6;
  int ve  = kt < 64 ? 50 : kt < 448 ? 439 : 823;   // valid end (padded coords)
  int off = kt < 64 ? 0  : kt < 448 ? 14  : 23;    // key' - off = real n
  __shared__ float Ls[96 * 68];
  int tid = threadIdx.x;
  size_t base = (size_t)b * NTOK;
  u16* vtlo = (bh < 32) ? (VtloA + (size_t)bh * BHSTR)
                        : (VtloB + (size_t)(bh - 32) * BHSTR);
  u16* kthi = Kthi + (size_t)bh * BHSTR;
  u16* ktlo = Ktlo + (size_t)bh * BHSTR;
  u16* vthi = Vthi + (size_t)bh * BHSTR;

  // ---- K: fragment-order convert
#pragma unroll
  for (int i = 0; i < 3; i++) {
    int c = i * 256 + tid;            // 768 = 64 keys x 12 d-chunks
    int key = c / 12, dc = c - key * 12;
    int kp = kt + key;
    uint4 hi4 = make_uint4(0, 0, 0, 0), lo4 = make_uint4(0, 0, 0, 0);
    if (kp < ve) {
      const float* p = qkv + (base + kp - off) * QKVD + DIM + h * HD + dc * 8;
      float4 a = *(const float4*)p;
      float4 e = *(const float4*)(p + 4);
      float xs[8] = {a.x, a.y, a.z, a.w, e.x, e.y, e.z, e.w};
      u32 hp[4], lp[4];
#pragma unroll
      for (int j = 0; j < 4; j++) {
        u32 b0 = asu(xs[2 * j]), b1 = asu(xs[2 * j + 1]);
        hp[j] = (b0 >> 16) | (b1 & 0xffff0000u);
        float l0 = xs[2 * j] - asf(b0 & 0xffff0000u);
        float l1 = xs[2 * j + 1] - asf(b1 & 0xffff0000u);
        lp[j] = (asu(l0) >> 16) | (asu(l1) & 0xffff0000u);
      }
      hi4 = make_uint4(hp[0], hp[1], hp[2], hp[3]);
      lo4 = make_uint4(lp[0], lp[1], lp[2], lp[3]);
    }
    int tile = (kt >> 5) + (key >> 5), key32 = key & 31;
    size_t go = ((size_t)tile * 384 + dc * 32 + key32) * 8;
    *(uint4*)(kthi + go) = hi4;
    *(uint4*)(ktlo + go) = lo4;
  }

  // ---- V: transpose via LDS, fragment-order emit
#pragma unroll
  for (int i = 0; i < 6; i++) {
    int c = i * 256 + tid;            // 1536 = 64 keys x 24 float4-chunks
    int key = c / 24, fc = c - key * 24;
    int kp = kt + key;
    float4 v = make_float4(0.f, 0.f, 0.f, 0.f);
    if (kp < ve)
      v = *(const float4*)(qkv + (base + kp - off) * QKVD + 2 * DIM + h * HD + fc * 4);
    Ls[(fc * 4 + 0) * 68 + key] = v.x;
    Ls[(fc * 4 + 1) * 68 + key] = v.y;
    Ls[(fc * 4 + 2) * 68 + key] = v.z;
    Ls[(fc * 4 + 3) * 68 + key] = v.w;
  }
  __syncthreads();
#pragma unroll
  for (int i = 0; i < 3; i++) {
    int c = i * 256 + tid;            // 768 = 2 tiles x 384 chunks
    int tl = c / 384, cc = c - tl * 384;
    int quad = cc / 96, d = cc - quad * 96;
    const float* ls = &Ls[d * 68 + tl * 32 + quad * 8];
    u32 hp[4], lp[4];
#pragma unroll
    for (int j = 0; j < 4; j++) {
      float x0v = ls[2 * j], x1v = ls[2 * j + 1];
      u32 b0 = asu(x0v), b1 = asu(x1v);
      hp[j] = (b0 >> 16) | (b1 & 0xffff0000u);
      float l0 = x0v - asf(b0 & 0xffff0000u);
      float l1 = x1v - asf(b1 & 0xffff0000u);
      lp[j] = (asu(l0) >> 16) | (asu(l1) & 0xffff0000u);
    }
    size_t go = ((size_t)((kt >> 5) + tl) * 384 + cc) * 8;
    *(uint4*)(vthi + go) = make_uint4(hp[0], hp[1], hp[2], hp[3]);
    *(uint4*)(vtlo + go) = make_uint4(lp[0], lp[1], lp[2], lp[3]);
  }
}

// ------------------------------------------- MFMA flash attention (r5 shape)
// 7 q-tiles x 64 bh. 128 q-rows/block, 4 waves x 2 row-frags of 16 rows.
// Double-buffered K/V staging; each 32-key tile's 12 K-ds_reads and 12
// V-ds_reads feed 72 MFMAs (2 row-frags share K/V fragments). Prefetch of
// tile it+1 is issued AFTER all current-tile LDS reads (K, sP, V) so any
// conservative vmcnt drain lands behind the PV MFMA cluster + barrier.
// One __syncthreads per tile. Per-row math order identical to the 64-row
// version -> bitwise-identical output. Output = RNE 2-plane bf16 A-planes.
__global__ __launch_bounds__(256, 2) void k_attn(const float* __restrict__ qkv,
                                              const u16* __restrict__ Kthi,
                                              const u16* __restrict__ Ktlo,
                                              const u16* __restrict__ Vthi,
                                              const u16* __restrict__ VtloA,
                                              const u16* __restrict__ VtloB,
                                              u16* __restrict__ ohi,
                                              u16* __restrict__ olo,
                                              int intra) {
  int t  = blockIdx.x >> 6;        // 0..6
  int bh = blockIdx.x & 63;
  int b = bh >> 3, h = bh & 7;

  int seg, q0, qlen;
  if (t == 0)      { seg = 0; q0 = 0;                    qlen = 50; }
  else if (t <= 3) { seg = 1; q0 = 50 + ((t - 1) << 7);  qlen = (425 - q0 < 128) ? (425 - q0) : 128; }
  else             { seg = 2; q0 = 425 + ((t - 4) << 7); qlen = (800 - q0 < 128) ? (800 - q0) : 128; }

  // key ranges in padded coords
  int r0s, r0e, r1s = 0, r1e = 0;
  if (intra) {
    r0s = (seg == 0) ? 0 : (seg == 1) ? 64 : 448;
    r0e = (seg == 0) ? 64 : (seg == 1) ? 448 : 832;
  } else {
    if (seg == 0)      { r0s = 64; r0e = 832; }
    else if (seg == 1) { r0s = 0;  r0e = 64;  r1s = 448; r1e = 832; }
    else               { r0s = 0;  r0e = 448; }
  }
  int n0t = (r0e - r0s) >> 5, n1t = (r1e - r1s) >> 5, nkt = n0t + n1t;

  __shared__ __align__(16) u16 sKV[2 * 12288];  // 2 x (Khi|Klo|Vhi|Vlo) 48KB
  __shared__ u32 sP[4][2 * 576];                // per-wave, per-frag P transpose

  int tid = threadIdx.x;
  int w = tid >> 6, lane = tid & 63, l15 = lane & 15, quad = lane >> 4;
  size_t base = (size_t)b * NTOK;
  const float sm0 = 0.10206207261596575f;   // 96^-0.5

  // staging source/dest precompute (loop-invariant per thread)
  const u16* sp0 = Kthi + (size_t)bh * BHSTR;
  const u16* sp1 = Ktlo + (size_t)bh * BHSTR;
  const u16* sp2 = Vthi + (size_t)bh * BHSTR;
  const u16* sp3 = (bh < 32) ? (VtloA + (size_t)bh * BHSTR)
                             : (VtloB + (size_t)(bh - 32) * BHSTR);
  const u16* sptr[6];
  u16* dptr[6];
#pragma unroll
  for (int j = 0; j < 6; j++) {
    int c = j * 256 + tid;           // 0..1535
    int rg = c / 384, cc = c - rg * 384;
    const u16* pb = rg == 0 ? sp0 : rg == 1 ? sp1 : rg == 2 ? sp2 : sp3;
    sptr[j] = pb + cc * 8;
    dptr[j] = &sKV[c * 8];
  }

  // ---- Q fragments (RNE 2-plane, pre-scaled) — wave w, frag f owns rows
  //      q0 + f*64 + w*16 .. +15
  bf16x8 qh[2][3], ql[2][3];
#pragma unroll
  for (int f = 0; f < 2; f++) {
    int q = q0 + f * 64 + w * 16 + l15; if (q > 799) q = 799;
    const float* qp = qkv + (base + q) * QKVD + h * HD;
#pragma unroll
    for (int df = 0; df < 3; df++) {
      float4 x0v = *(const float4*)(qp + df * 32 + quad * 8);
      float4 x1v = *(const float4*)(qp + df * 32 + quad * 8 + 4);
      float xs[8] = {x0v.x, x0v.y, x0v.z, x0v.w, x1v.x, x1v.y, x1v.z, x1v.w};
#pragma unroll
      for (int j = 0; j < 8; j++) {
        float x = xs[j] * sm0;
        u16 hu = f2bf(x);
        u16 lu = f2bf(x - bf2f(hu));
        qh[f][df][j] = (short)hu; ql[f][df][j] = (short)lu;
      }
    }
  }

  f32x4 oacc[2][6];
#pragma unroll
  for (int f = 0; f < 2; f++)
#pragma unroll
    for (int c = 0; c < 6; c++) oacc[f][c] = (f32x4){0.f, 0.f, 0.f, 0.f};
  float m_i[2][4], l_i[2][4];
#pragma unroll
  for (int f = 0; f < 2; f++)
#pragma unroll
    for (int r = 0; r < 4; r++) { m_i[f][r] = -1e30f; l_i[f][r] = 0.f; }

  u32* sPw = sP[w];

  // ---- prologue: stage tile 0 into buf 0; barrier drains vmcnt
  {
    size_t toff = (size_t)(r0s >> 5) * 3072;
#pragma unroll
    for (int j = 0; j < 6; j++) async16(sptr[j] + toff, dptr[j]);
  }
  __syncthreads();                   // buf0 staged & visible

  for (int it = 0; it < nkt; it++) {
    int kt = (it < n0t) ? (r0s + (it << 5)) : (r1s + ((it - n0t) << 5));
    int ve = kt < 64 ? 50 : kt < 448 ? 439 : 823;
    int cur = it & 1;
    int cbo = cur * 12288;           // current buffer u16 offset

    // ---- S = Q K^T  (K frags read once, feed both row-frags)
    f32x4 Sf[2][2];
#pragma unroll
    for (int f = 0; f < 2; f++)
#pragma unroll
      for (int h2 = 0; h2 < 2; h2++) Sf[f][h2] = (f32x4){0.f, 0.f, 0.f, 0.f};
#pragma unroll
    for (int h2 = 0; h2 < 2; h2++)
#pragma unroll
      for (int df = 0; df < 3; df++) {
        int co = cbo + ((df * 4 + quad) * 32 + h2 * 16 + l15) * 8;
        bf16x8 kh = *(const bf16x8*)&sKV[co];
        bf16x8 kl = *(const bf16x8*)&sKV[3072 + co];
#pragma unroll
        for (int f = 0; f < 2; f++) {
          Sf[f][h2] = __builtin_amdgcn_mfma_f32_16x16x32_bf16(qh[f][df], kh, Sf[f][h2], 0, 0, 0);
          Sf[f][h2] = __builtin_amdgcn_mfma_f32_16x16x32_bf16(ql[f][df], kh, Sf[f][h2], 0, 0, 0);
          Sf[f][h2] = __builtin_amdgcn_mfma_f32_16x16x32_bf16(qh[f][df], kl, Sf[f][h2], 0, 0, 0);
        }
      }
#pragma unroll
    for (int f = 0; f < 2; f++) {
      if (kt + l15 >= ve)      Sf[f][0] = (f32x4){-1e30f, -1e30f, -1e30f, -1e30f};
      if (kt + 16 + l15 >= ve) Sf[f][1] = (f32x4){-1e30f, -1e30f, -1e30f, -1e30f};
    }

    // ---- online softmax (8 rows, reductions run in parallel)
    float mx[2][4], al[2][4], ps0[2][4], ps1[2][4], rs[2][4];
#pragma unroll
    for (int f = 0; f < 2; f++)
#pragma unroll
      for (int r = 0; r < 4; r++) mx[f][r] = fmaxf(Sf[f][0][r], Sf[f][1][r]);
#pragma unroll
    for (int o = 1; o < 16; o <<= 1)
#pragma unroll
      for (int f = 0; f < 2; f++)
#pragma unroll
        for (int r = 0; r < 4; r++) mx[f][r] = fmaxf(mx[f][r], __shfl_xor(mx[f][r], o, 64));
#pragma unroll
    for (int f = 0; f < 2; f++)
#pragma unroll
      for (int r = 0; r < 4; r++) {
        float mn = fmaxf(m_i[f][r], mx[f][r]);
        al[f][r] = __expf(m_i[f][r] - mn);
        m_i[f][r] = mn;
        ps0[f][r] = __expf(Sf[f][0][r] - mn);
        ps1[f][r] = __expf(Sf[f][1][r] - mn);
        rs[f][r] = ps0[f][r] + ps1[f][r];
      }
#pragma unroll
    for (int o = 1; o < 16; o <<= 1)
#pragma unroll
      for (int f = 0; f < 2; f++)
#pragma unroll
        for (int r = 0; r < 4; r++) rs[f][r] += __shfl_xor(rs[f][r], o, 64);
#pragma unroll
    for (int f = 0; f < 2; f++)
#pragma unroll
      for (int r = 0; r < 4; r++) l_i[f][r] = l_i[f][r] * al[f][r] + rs[f][r];

    // ---- pack P (trunc 2-plane), transpose via per-wave LDS (intra-wave)
    bf16x8 ph[2], pl[2];
#pragma unroll
    for (int f = 0; f < 2; f++) {
      u32* sPf = sPw + f * 576;
#pragma unroll
      for (int r = 0; r < 4; r++) {
        u32 b0 = asu(ps0[f][r]);
        float lo0 = ps0[f][r] - asf(b0 & 0xffff0000u);
        sPf[(quad * 4 + r) * 36 + l15] = (b0 >> 16) | (asu(lo0) & 0xffff0000u);
        u32 b1 = asu(ps1[f][r]);
        float lo1 = ps1[f][r] - asf(b1 & 0xffff0000u);
        sPf[(quad * 4 + r) * 36 + 16 + l15] = (b1 >> 16) | (asu(lo1) & 0xffff0000u);
      }
    }
    asm volatile("" ::: "memory");   // intra-wave LDS in-order; block reordering
#pragma unroll
    for (int f = 0; f < 2; f++) {
      u32* sPf = sPw + f * 576;
      uint4 t0 = *(const uint4*)&sPf[l15 * 36 + quad * 8];
      uint4 t1 = *(const uint4*)&sPf[l15 * 36 + quad * 8 + 4];
      u32 tt[8] = {t0.x, t0.y, t0.z, t0.w, t1.x, t1.y, t1.z, t1.w};
#pragma unroll
      for (int j = 0; j < 8; j++) {
        ph[f][j] = (short)(tt[j] & 0xffffu);
        pl[f][j] = (short)(tt[j] >> 16);
      }
    }

    // ---- bulk V fragment read (last LDS reads of the current tile)
    bf16x8 vh[6], vl[6];
#pragma unroll
    for (int c = 0; c < 6; c++) {
      int co = cbo + (quad * 96 + c * 16 + l15) * 8;
      vh[c] = *(const bf16x8*)&sKV[2 * 3072 + co];
      vl[c] = *(const bf16x8*)&sKV[3 * 3072 + co];
    }

    // ---- stage tile it+1 into buf[cur^1]: issued after ALL current-tile
    //      LDS reads, so a conservative vmcnt drain can only land behind
    //      the PV MFMA cluster + end-of-tile barrier.
    if (it + 1 < nkt) {
      int kn = (it + 1 < n0t) ? (r0s + ((it + 1) << 5))
                              : (r1s + ((it + 1 - n0t) << 5));
      size_t toff = (size_t)(kn >> 5) * 3072;
      int nbo = (cur ^ 1) * 12288;
#pragma unroll
      for (int j = 0; j < 6; j++) async16(sptr[j] + toff, dptr[j] + nbo);
    }

    // ---- rescale O, then O += P V (V frags shared by both row-frags)
#pragma unroll
    for (int f = 0; f < 2; f++) {
      f32x4 alv = {al[f][0], al[f][1], al[f][2], al[f][3]};
#pragma unroll
      for (int c = 0; c < 6; c++) oacc[f][c] *= alv;
    }
#pragma unroll
    for (int f = 0; f < 2; f++)
#pragma unroll
      for (int c = 0; c < 6; c++) {
        oacc[f][c] = __builtin_amdgcn_mfma_f32_16x16x32_bf16(ph[f], vh[c], oacc[f][c], 0, 0, 0);
        oacc[f][c] = __builtin_amdgcn_mfma_f32_16x16x32_bf16(ph[f], vl[c], oacc[f][c], 0, 0, 0);
        oacc[f][c] = __builtin_amdgcn_mfma_f32_16x16x32_bf16(pl[f], vh[c], oacc[f][c], 0, 0, 0);
      }

    // ---- single barrier: seals reads of buf[cur] (next iter overwrites it)
    //      and drains the just-issued stage of buf[cur^1]
    __syncthreads();
  }

  // ---- epilogue: RNE 2-plane A-operand output
#pragma unroll
  for (int f = 0; f < 2; f++) {
    float inv[4];
#pragma unroll
    for (int r = 0; r < 4; r++) inv[r] = 1.0f / l_i[f][r];
#pragma unroll
    for (int c = 0; c < 6; c++)
#pragma unroll
      for (int r = 0; r < 4; r++) {
        int rl = f * 64 + w * 16 + quad * 4 + r;
        if (rl < qlen) {
          float v = oacc[f][c][r] * inv[r];
          size_t idx = (base + q0 + rl) * DIM + h * HD + c * 16 + l15;
          u16 hu = f2bf(v);
          ohi[idx] = hu;
          olo[idx] = f2bf(v - bf2f(hu));
        }
      }
  }
}

// ---------------------------------------------------------------- layernorm
__global__ __launch_bounds__(256) void k_ln(const float* __restrict__ x,
                                            const float* __restrict__ g,
                                            const float* __restrict__ be,
                                            float* __restrict__ outp) {
  int row = blockIdx.x;
  const float* xr = x + (size_t)row * DIM;
  float v[3]; float s = 0.f;
#pragma unroll
  for (int i = 0; i < 3; i++) { v[i] = xr[threadIdx.x + (i << 8)]; s += v[i]; }
#pragma unroll
  for (int off = 1; off < 64; off <<= 1) s += __shfl_xor(s, off, 64);
  __shared__ float red[4];
  int wv = threadIdx.x >> 6;
  if ((threadIdx.x & 63) == 0) red[wv] = s;
  __syncthreads();
  float mu = (red[0] + red[1] + red[2] + red[3]) * (1.0f / 768.0f);
  float sq = 0.f;
#pragma unroll
  for (int i = 0; i < 3; i++) { float d2 = v[i] - mu; sq += d2 * d2; }
#pragma unroll
  for (int off = 1; off < 64; off <<= 1) sq += __shfl_xor(sq, off, 64);
  __syncthreads();
  if ((threadIdx.x & 63) == 0) red[wv] = sq;
  __syncthreads();
  float var = (red[0] + red[1] + red[2] + red[3]) * (1.0f / 768.0f);
  float rstd = rsqrtf(var + 1e-5f);
  float* orow = outp + (size_t)row * DIM;
#pragma unroll
  for (int i = 0; i < 3; i++) {
    int d = threadIdx.x + (i << 8);
    orow[d] = (v[i] - mu) * rstd * g[d] + be[d];
  }
}

// ---------------------------------------------------------------- launch
extern "C" void kernel_launch(void* const* d_in, const int* in_sizes, int n_in,
                              void* d_out, int out_size, void* d_ws, size_t ws_size,
                              hipStream_t stream) {
  (void)in_sizes; (void)n_in; (void)out_size; (void)ws_size;
  const float* seq0 = (const float*)d_in[0];
  const float* seq1 = (const float*)d_in[1];
  const float* seq2 = (const float*)d_in[2];

  const size_t NX   = (size_t)ROWS * DIM;    // 4,915,200
  const size_t NQKV = (size_t)ROWS * QKVD;   // 14,745,600
  const int WIN_N   = QKVD * DIM;            // 1,769,472
  const int WOUT_N  = DIM * DIM;             //   589,824
  const size_t PLN  = (size_t)64 * BHSTR;    // 5,111,808 u16 per plane

  // ws (128.19 MiB): x0 | qkv | att | X | S.  Time-shared overlays per layer:
  //   x0 region (2NX u16): P1 planes (A of QKV gemm) -> Kthi + VtloA (attn)
  //   att region (2NX u16): embed floats (pre-l0) -> P2 planes (attn out = A
  //                         of out-proj gemm)
  //   X region (2NX u16): Ktlo + VtloB (attn); X floats written only at l==3
  //   S region (PLN u16): WP planes (gemms) <-> Vthi (attn)
  float* x0   = (float*)d_ws;
  float* qkvb = x0   + NX;
  float* att  = qkvb + NQKV;
  float* X    = att  + NX;
  u16*   S    = (u16*)(X + NX);
  u16*   WPh  = S;            u16* WPl  = S + WIN_N;
  u16*   Vthi = S;
  u16*   P1h  = (u16*)x0;     u16* P1l  = P1h + NX;
  u16*   P2h  = (u16*)att;    u16* P2l  = P2h + NX;
  u16*   Kthi = (u16*)x0;     u16* VtloA = Kthi + PLN;   // 32 bh
  u16*   Ktlo = (u16*)X;      u16* VtloB = Ktlo + PLN;   // 32 bh

  for (int g = 0; g < 2; g++) {           // g=0: inter, g=1: intra
    const float* w_in  = (const float*)d_in[3 + 6 * g];
    const float* b_in  = (const float*)d_in[4 + 6 * g];
    const float* w_out = (const float*)d_in[5 + 6 * g];
    const float* b_out = (const float*)d_in[6 + 6 * g];
    const float* ln_g  = (const float*)d_in[7 + 6 * g];
    const float* ln_b  = (const float*)d_in[8 + 6 * g];

    k_embed<<<ROWS, 256, 0, stream>>>(seq0, seq1, seq2, att);

    for (int l = 0; l < 4; l++) {
      if (l == 0)
        k_conv<<<(int)(NX / 8 / 256), 256, 0, stream>>>(att, P1h, P1l, (int)(NX / 8));
      k_conv<<<WIN_N / 8 / 256, 256, 0, stream>>>(
          w_in + (size_t)l * WIN_N, WPh, WPl, WIN_N / 8);
      k_gemm_qkv<<<dim3(QKVD / 256, ROWS / 256), 512, 0, stream>>>(
          P1h, P1l, WPh, WPl, b_in + (size_t)l * QKVD, qkvb, QKVD, DIM);

      k_convkv<<<13 * 64, 256, 0, stream>>>(qkvb, Kthi, Ktlo, Vthi, VtloA, VtloB);
      k_attn<<<7 * 64, 256, 0, stream>>>(qkvb, Kthi, Ktlo, Vthi, VtloA, VtloB,
                                         P2h, P2l, g);

      k_conv<<<WOUT_N / 8 / 256, 256, 0, stream>>>(
          w_out + (size_t)l * WOUT_N, WPh, WPl, WOUT_N / 8);
      k_gemm_out<<<dim3(DIM / 128, ROWS / 128), 256, 0, stream>>>(
          P2h, P2l, WPh, WPl, b_out + (size_t)l * DIM, X,
          P1h, P1l, (l == 3) ? 1 : 0, DIM, DIM);
    }
    k_ln<<<ROWS, 256, 0, stream>>>(X, ln_g, ln_b,
                                   (float*)d_out + (size_t)g * ROWS * DIM);
  }
}

// Round 8
// 1565.672 us; speedup vs baseline: 1.0568x; 1.0518x over previous
//
#include <hip/hip_runtime.h>
#include <math.h>

// FusionShiftingGraph: two 4-layer no-residual transformer stacks + final LN.
// Round 13: k_attn moved to 32x32x16 MFMA with swapped operands so softmax is
// lane-local (r7 analysis: LDS pipe was the wall — 64 bpermutes/tile for the
// shfl butterflies + 24 sP ops).  S = mfma32(K,Q): lane owns q=lane&31's full
// row; max/sum = in-reg tree + ONE shfl_xor(32).  P->B-operand redistribution
// via cvt-pack + v_permlane32_swap (pure VALU).  PV as O^T = mfma32(V^T, P)
// puts O back in the q=lane&31 domain -> stats apply with no redistribution;
// sP buffer deleted (LDS 67.6->48KB).  LDS ops/tile/wave 104 -> 24.
// k_convkv re-emits K/V planes in 32x32 A-frag layouts (same sizes/strides,
// same per-value trunc conversion).  GEMMs/embed/conv/ln unchanged.
//
// Segments: [0,50) [50,425) [425,800).  B=8, N=800, D=768, H=8, hd=96.

#define NTOK 800
#define ROWS 6400          // B*N
#define DIM 768
#define QKVD 2304
#define HD 96
#define NTILE 26           // padded key space 832 = 26 x 32
#define BHSTR 79872        // per-bh plane stride (26*384*8 u16)

typedef unsigned short u16;
typedef unsigned int u32;
using bf16x8 = __attribute__((ext_vector_type(8))) short;   // 8 bf16 (4 VGPRs)
using f32x4  = __attribute__((ext_vector_type(4))) float;
using f32x16 = __attribute__((ext_vector_type(16))) float;

__device__ __forceinline__ u16 f2bf(float x) {            // RNE fp32->bf16
  union { float f; u32 u; } v; v.f = x;
  u32 r = v.u + 0x7fffu + ((v.u >> 16) & 1u);
  return (u16)(r >> 16);
}
__device__ __forceinline__ float bf2f(u16 h) {
  union { u32 u; float f; } v; v.u = ((u32)h) << 16;
  return v.f;
}
__device__ __forceinline__ u32 asu(float x) { union { float f; u32 u; } v; v.f = x; return v.u; }
__device__ __forceinline__ float asf(u32 x) { union { u32 u; float f; } v; v.u = x; return v.f; }
__device__ __forceinline__ void async16(const u16* g, u16* l) {
  __builtin_amdgcn_global_load_lds((const __attribute__((address_space(1))) u32*)g,
                                   (__attribute__((address_space(3))) u32*)l,
                                   16, 0, 0);
}
// bijective XCD chunk remap (m204): consecutive new-ids land on one XCD
__device__ __forceinline__ int xcd_swz(int orig, int nblk) {
  int cq = nblk >> 3, cr = nblk & 7;
  int xcd = orig & 7, pos = orig >> 3;
  return (xcd < cr ? xcd * (cq + 1) : cr * (cq + 1) + (xcd - cr) * cq) + pos;
}

// ---------------------------------------------------------------- embed
__global__ __launch_bounds__(256) void k_embed(const float* __restrict__ s0,
                                               const float* __restrict__ s1,
                                               const float* __restrict__ s2,
                                               float* __restrict__ x) {
  int row = blockIdx.x;            // 0..6399
  int b = row / NTOK, n = row % NTOK;
  const float* src; int ln;
  if (n < 50)       { src = s0 + ((size_t)b * 50  + n)         * DIM; ln = n; }
  else if (n < 425) { src = s1 + ((size_t)b * 375 + (n - 50))  * DIM; ln = n - 50; }
  else              { src = s2 + ((size_t)b * 375 + (n - 425)) * DIM; ln = n - 425; }
  float p = (float)(ln + 2);       // fairseq: positions start at padding_idx+1=2
  const float negk = -0.024047108543801f;   // -ln(10000)/383
  float* dst = x + (size_t)row * DIM;
  for (int i = 0; i < 3; i++) {
    int d = threadIdx.x + (i << 8);
    int dd = (d < 384) ? d : d - 384;
    float ang = p * expf((float)dd * negk);
    float pe = (d < 384) ? sinf(ang) : cosf(ang);
    dst[d] = 27.712812921102035f * src[d] + pe;   // sqrt(768)*s + pe
  }
}

// ------------------------------------------------- fp32 -> (hi,lo) bf16 planes
__global__ __launch_bounds__(256) void k_conv(const float* __restrict__ x,
                                              u16* __restrict__ hi,
                                              u16* __restrict__ lo, int n8) {
  int i = blockIdx.x * 256 + threadIdx.x;   // 8 elems / thread
  if (i >= n8) return;
  float4 a = ((const float4*)x)[i * 2];
  float4 b = ((const float4*)x)[i * 2 + 1];
  float v[8] = {a.x, a.y, a.z, a.w, b.x, b.y, b.z, b.w};
  u32 hp[4], lp[4];
#pragma unroll
  for (int j = 0; j < 4; j++) {
    u16 h0 = f2bf(v[2 * j]), h1 = f2bf(v[2 * j + 1]);
    u16 l0 = f2bf(v[2 * j] - bf2f(h0));
    u16 l1 = f2bf(v[2 * j + 1] - bf2f(h1));
    hp[j] = (u32)h0 | ((u32)h1 << 16);
    lp[j] = (u32)l0 | ((u32)l1 << 16);
  }
  ((uint4*)hi)[i] = make_uint4(hp[0], hp[1], hp[2], hp[3]);
  ((uint4*)lo)[i] = make_uint4(lp[0], lp[1], lp[2], lp[3]);
}

// ------------------------------------------- pipelined 128^2 split-bf16 GEMM
// Out-projection. C = A*W^T + bias; optional fp32 store (wantF) and/or 2-plane
// bf16 store (Chi/Clo) feeding the next GEMM's A-operand.
__global__ __launch_bounds__(256, 2) void k_gemm_out(
    const u16* __restrict__ Ah, const u16* __restrict__ Al,
    const u16* __restrict__ Bh, const u16* __restrict__ Bl,
    const float* __restrict__ bias, float* __restrict__ C,
    u16* __restrict__ Chi, u16* __restrict__ Clo, int wantF,
    int N, int K) {
  __shared__ __align__(16) u16 sm[2 * 16384];   // 64 KB
  int tid = threadIdx.x;
  int wave = tid >> 6, lane = tid & 63;
  int l15 = lane & 15, quad = lane >> 4;
  int wr = wave >> 1, wc = wave & 1;            // 2x2 waves, each 64x64
  int nbx = (int)gridDim.x;
  int nblk = nbx * (int)gridDim.y;
  int orig = (int)blockIdx.y * nbx + (int)blockIdx.x;
  int nid = xcd_swz(orig, nblk);
  int by = nid / nbx, bx = nid - by * nbx;
  int m0 = by << 7, n0 = bx << 7;

  int srow = tid >> 2, sp = tid & 3;
  int offE = srow * K + ((sp ^ ((srow >> 1) & 3)) << 3);
  int offO = offE + (K << 6);                   // +64 rows (XOR phase invariant)
  const u16* Agh = Ah + (size_t)m0 * K;
  const u16* Agl = Al + (size_t)m0 * K;
  const u16* Bgh = Bh + (size_t)n0 * K;
  const u16* Bgl = Bl + (size_t)n0 * K;
  u16* lb = &sm[tid * 8];

  f32x4 acc[4][4];
#pragma unroll
  for (int i = 0; i < 4; i++)
#pragma unroll
    for (int j = 0; j < 4; j++) acc[i][j] = (f32x4){0.f, 0.f, 0.f, 0.f};

  int nk = K >> 5;                              // 24 K-steps
  int qoff = (quad ^ ((l15 >> 1) & 3)) << 3;    // frag-read XOR swizzle
  int abase = ((wr << 6) + l15) * 32 + qoff;            // A-frag LDS base
  int bbase = 8192 + ((wc << 6) + l15) * 32 + qoff;     // B-frag LDS base

#define STG(bsel, koff) {                         \
    u16* d_ = lb + ((bsel) << 14);                \
    async16(Agh + offE + (koff), d_);             \
    async16(Agh + offO + (koff), d_ + 2048);      \
    async16(Agl + offE + (koff), d_ + 4096);      \
    async16(Agl + offO + (koff), d_ + 6144);      \
    async16(Bgh + offE + (koff), d_ + 8192);      \
    async16(Bgh + offO + (koff), d_ + 10240);     \
    async16(Bgl + offE + (koff), d_ + 12288);     \
    async16(Bgl + offO + (koff), d_ + 14336); }

  STG(0, 0);
  STG(1, 32);
  asm volatile("s_waitcnt vmcnt(8)" ::: "memory");   // buf0's 8 loads landed
  __builtin_amdgcn_s_barrier();
  asm volatile("" ::: "memory");

  bf16x8 aLh[2], aLv[2], bLh[2], bLv[2];
  {
    const u16* sa = &sm[abase];
    const u16* sb = &sm[bbase];
#pragma unroll
    for (int i = 0; i < 2; i++) {
      aLh[i] = *(const bf16x8*)(sa + i * 512);
      aLv[i] = *(const bf16x8*)(sa + 4096 + i * 512);
    }
#pragma unroll
    for (int j = 0; j < 2; j++) {
      bLh[j] = *(const bf16x8*)(sb + j * 512);
      bLv[j] = *(const bf16x8*)(sb + 4096 + j * 512);
    }
  }

  for (int t = 0; t < nk; ++t) {
    asm volatile("" ::: "memory");
    int bufo = (t & 1) << 14;
    int nxto = ((t + 1) & 1) << 14;
    const u16* sa = &sm[bufo + abase];
    const u16* sb = &sm[bufo + bbase];
    const u16* na = &sm[nxto + abase];
    const u16* nb = &sm[nxto + bbase];
    bf16x8 aHh[2], aHv[2], bHh[2], bHv[2];

    // ---- LL: read-ahead bH; MFMA (i0-1)x(j0-1)
#pragma unroll
    for (int j = 0; j < 2; j++) {
      bHh[j] = *(const bf16x8*)(sb + (j + 2) * 512);
      bHv[j] = *(const bf16x8*)(sb + 4096 + (j + 2) * 512);
    }
    __builtin_amdgcn_s_setprio(1);
#pragma unroll
    for (int i = 0; i < 2; i++)
#pragma unroll
      for (int j = 0; j < 2; j++) {
        acc[i][j] = __builtin_amdgcn_mfma_f32_16x16x32_bf16(aLh[i], bLh[j], acc[i][j], 0, 0, 0);
        acc[i][j] = __builtin_amdgcn_mfma_f32_16x16x32_bf16(aLh[i], bLv[j], acc[i][j], 0, 0, 0);
        acc[i][j] = __builtin_amdgcn_mfma_f32_16x16x32_bf16(aLv[i], bLh[j], acc[i][j], 0, 0, 0);
      }
    __builtin_amdgcn_s_setprio(0);

    // ---- LH: read-ahead aH; MFMA (i0-1)x(j2-3)
#pragma unroll
    for (int i = 0; i < 2; i++) {
      aHh[i] = *(const bf16x8*)(sa + (i + 2) * 512);
      aHv[i] = *(const bf16x8*)(sa + 4096 + (i + 2) * 512);
    }
    __builtin_amdgcn_s_setprio(1);
#pragma unroll
    for (int i = 0; i < 2; i++)
#pragma unroll
      for (int j = 0; j < 2; j++) {
        acc[i][j + 2] = __builtin_amdgcn_mfma_f32_16x16x32_bf16(aLh[i], bHh[j], acc[i][j + 2], 0, 0, 0);
        acc[i][j + 2] = __builtin_amdgcn_mfma_f32_16x16x32_bf16(aLh[i], bHv[j], acc[i][j + 2], 0, 0, 0);
        acc[i][j + 2] = __builtin_amdgcn_mfma_f32_16x16x32_bf16(aLv[i], bHh[j], acc[i][j + 2], 0, 0, 0);
      }
    __builtin_amdgcn_s_setprio(0);

    // ---- HL: MFMA (i2-3)x(j0-1); bL dead after
    __builtin_amdgcn_s_setprio(1);
#pragma unroll
    for (int i = 0; i < 2; i++)
#pragma unroll
      for (int j = 0; j < 2; j++) {
        acc[i + 2][j] = __builtin_amdgcn_mfma_f32_16x16x32_bf16(aHh[i], bLh[j], acc[i + 2][j], 0, 0, 0);
        acc[i + 2][j] = __builtin_amdgcn_mfma_f32_16x16x32_bf16(aHh[i], bLv[j], acc[i + 2][j], 0, 0, 0);
        acc[i + 2][j] = __builtin_amdgcn_mfma_f32_16x16x32_bf16(aHv[i], bLh[j], acc[i + 2][j], 0, 0, 0);
      }
    __builtin_amdgcn_s_setprio(0);

    // ---- hand-off
    asm volatile("s_waitcnt lgkmcnt(0)" ::: "memory");
    __builtin_amdgcn_s_barrier();              // all waves done reading cur
    asm volatile("" ::: "memory");
    {
      int kn = (t + 2 < nk) ? ((t + 2) << 5) : 0;   // tail: dead re-stage
      STG(t & 1, kn);
    }
    asm volatile("s_waitcnt vmcnt(8)" ::: "memory"); // nxt buffer landed
    __builtin_amdgcn_s_barrier();
    asm volatile("" ::: "memory");

    // ---- boundary reads (nxt aL,bL) overlap the HH MFMA cluster
#pragma unroll
    for (int i = 0; i < 2; i++) {
      aLh[i] = *(const bf16x8*)(na + i * 512);
      aLv[i] = *(const bf16x8*)(na + 4096 + i * 512);
    }
#pragma unroll
    for (int j = 0; j < 2; j++) {
      bLh[j] = *(const bf16x8*)(nb + j * 512);
      bLv[j] = *(const bf16x8*)(nb + 4096 + j * 512);
    }
    // ---- HH: MFMA (i2-3)x(j2-3)
    __builtin_amdgcn_s_setprio(1);
#pragma unroll
    for (int i = 0; i < 2; i++)
#pragma unroll
      for (int j = 0; j < 2; j++) {
        acc[i + 2][j + 2] = __builtin_amdgcn_mfma_f32_16x16x32_bf16(aHh[i], bHh[j], acc[i + 2][j + 2], 0, 0, 0);
        acc[i + 2][j + 2] = __builtin_amdgcn_mfma_f32_16x16x32_bf16(aHh[i], bHv[j], acc[i + 2][j + 2], 0, 0, 0);
        acc[i + 2][j + 2] = __builtin_amdgcn_mfma_f32_16x16x32_bf16(aHv[i], bHh[j], acc[i + 2][j + 2], 0, 0, 0);
      }
    __builtin_amdgcn_s_setprio(0);
  }
#undef STG

  asm volatile("s_waitcnt vmcnt(0)" ::: "memory");   // drain tail stages
  __builtin_amdgcn_s_barrier();

  // ---- epilogue: fp32 + bias and/or RNE 2-plane bf16
#pragma unroll
  for (int i = 0; i < 4; i++) {
    int row0 = m0 + wr * 64 + i * 16 + quad * 4;
#pragma unroll
    for (int j = 0; j < 4; j++) {
      int col = n0 + wc * 64 + j * 16 + l15;
      float bv = bias[col];
#pragma unroll
      for (int r = 0; r < 4; r++) {
        size_t idx = (size_t)(row0 + r) * N + col;
        float v = acc[i][j][r] + bv;
        if (wantF) C[idx] = v;
        if (Chi) {
          u16 hu = f2bf(v);
          Chi[idx] = hu;
          Clo[idx] = f2bf(v - bf2f(hu));
        }
      }
    }
  }
}

// ------------------------------------------- 256x256 pipelined split-bf16 GEMM
// QKV projection. 512 threads = 8 waves (2x4), each wave 128x64; BK=32,
// depth-2 128KB LDS, counted vmcnt(8), quadrants LL->LH->HL->HH with
// read-ahead, 2 barriers/K-step. XCD chunk swizzle.
__global__ __launch_bounds__(512, 2) void k_gemm_qkv(
    const u16* __restrict__ Ah, const u16* __restrict__ Al,
    const u16* __restrict__ Bh, const u16* __restrict__ Bl,
    const float* __restrict__ bias, float* __restrict__ C,
    int N, int K) {
  __shared__ __align__(16) u16 sm[2 * 32768];   // 128 KB
  int tid = threadIdx.x;
  int wave = tid >> 6, lane = tid & 63;
  int l15 = lane & 15, quad = lane >> 4;
  int wr = wave >> 2, wc = wave & 3;            // 2 (row) x 4 (col) waves
  int nbx = (int)gridDim.x;
  int nblk = nbx * (int)gridDim.y;
  int orig = (int)blockIdx.y * nbx + (int)blockIdx.x;
  int nid = xcd_swz(orig, nblk);
  int by = nid / nbx, bx = nid - by * nbx;
  int m0 = by << 8, n0 = bx << 8;

  int srow = tid >> 2, sp = tid & 3;
  int offE = srow * K + ((sp ^ ((srow >> 1) & 3)) << 3);
  int offO = offE + (K << 7);                   // +128 rows
  const u16* Agh = Ah + (size_t)m0 * K;
  const u16* Agl = Al + (size_t)m0 * K;
  const u16* Bgh = Bh + (size_t)n0 * K;
  const u16* Bgl = Bl + (size_t)n0 * K;
  u16* lb = &sm[tid * 8];

  f32x4 acc[8][4];
#pragma unroll
  for (int i = 0; i < 8; i++)
#pragma unroll
    for (int j = 0; j < 4; j++) acc[i][j] = (f32x4){0.f, 0.f, 0.f, 0.f};

  int nk = K >> 5;                              // 24 K-steps
  int qoff = (quad ^ ((l15 >> 1) & 3)) << 3;    // frag-read XOR swizzle
  int abase = ((wr << 7) + l15) * 32 + qoff;            // A-frag LDS base
  int bbase = 16384 + ((wc << 6) + l15) * 32 + qoff;    // B-frag LDS base

#define STG(bsel, koff) {                         \
    u16* d_ = lb + ((bsel) << 15);                \
    async16(Agh + offE + (koff), d_);             \
    async16(Agh + offO + (koff), d_ + 4096);      \
    async16(Agl + offE + (koff), d_ + 8192);      \
    async16(Agl + offO + (koff), d_ + 12288);     \
    async16(Bgh + offE + (koff), d_ + 16384);     \
    async16(Bgh + offO + (koff), d_ + 20480);     \
    async16(Bgl + offE + (koff), d_ + 24576);     \
    async16(Bgl + offO + (koff), d_ + 28672); }

  STG(0, 0);
  STG(1, 32);
  asm volatile("s_waitcnt vmcnt(8)" ::: "memory");   // buf0's 8 loads landed
  __builtin_amdgcn_s_barrier();
  asm volatile("" ::: "memory");

  bf16x8 aLh[4], aLv[4], bLh[2], bLv[2];
  {
    const u16* sa = &sm[abase];
    const u16* sb = &sm[bbase];
#pragma unroll
    for (int i = 0; i < 4; i++) {
      aLh[i] = *(const bf16x8*)(sa + i * 512);
      aLv[i] = *(const bf16x8*)(sa + 8192 + i * 512);
    }
#pragma unroll
    for (int j = 0; j < 2; j++) {
      bLh[j] = *(const bf16x8*)(sb + j * 512);
      bLv[j] = *(const bf16x8*)(sb + 8192 + j * 512);
    }
  }

  for (int t = 0; t < nk; ++t) {
    asm volatile("" ::: "memory");
    int bufo = (t & 1) << 15;
    int nxto = ((t + 1) & 1) << 15;
    const u16* sa = &sm[bufo + abase];
    const u16* sb = &sm[bufo + bbase];
    const u16* na = &sm[nxto + abase];
    const u16* nb = &sm[nxto + bbase];
    bf16x8 aHh[4], aHv[4], bHh[2], bHv[2];

    // ---- LL: read-ahead bH(cur); MFMA acc[i0-3][j0-1] (aL x bL)
#pragma unroll
    for (int j = 0; j < 2; j++) {
      bHh[j] = *(const bf16x8*)(sb + (j + 2) * 512);
      bHv[j] = *(const bf16x8*)(sb + 8192 + (j + 2) * 512);
    }
    __builtin_amdgcn_s_setprio(1);
#pragma unroll
    for (int i = 0; i < 4; i++)
#pragma unroll
      for (int j = 0; j < 2; j++) {
        acc[i][j] = __builtin_amdgcn_mfma_f32_16x16x32_bf16(aLh[i], bLh[j], acc[i][j], 0, 0, 0);
        acc[i][j] = __builtin_amdgcn_mfma_f32_16x16x32_bf16(aLh[i], bLv[j], acc[i][j], 0, 0, 0);
        acc[i][j] = __builtin_amdgcn_mfma_f32_16x16x32_bf16(aLv[i], bLh[j], acc[i][j], 0, 0, 0);
      }
    __builtin_amdgcn_s_setprio(0);

    // ---- LH: read-ahead aH(cur); MFMA acc[i0-3][j2-3] (aL x bH)
#pragma unroll
    for (int i = 0; i < 4; i++) {
      aHh[i] = *(const bf16x8*)(sa + (i + 4) * 512);
      aHv[i] = *(const bf16x8*)(sa + 8192 + (i + 4) * 512);
    }
    __builtin_amdgcn_s_setprio(1);
#pragma unroll
    for (int i = 0; i < 4; i++)
#pragma unroll
      for (int j = 0; j < 2; j++) {
        acc[i][j + 2] = __builtin_amdgcn_mfma_f32_16x16x32_bf16(aLh[i], bHh[j], acc[i][j + 2], 0, 0, 0);
        acc[i][j + 2] = __builtin_amdgcn_mfma_f32_16x16x32_bf16(aLh[i], bHv[j], acc[i][j + 2], 0, 0, 0);
        acc[i][j + 2] = __builtin_amdgcn_mfma_f32_16x16x32_bf16(aLv[i], bHh[j], acc[i][j + 2], 0, 0, 0);
      }
    __builtin_amdgcn_s_setprio(0);

    // ---- HL: MFMA acc[i4-7][j0-1] (aH x bL); bL dead after
    __builtin_amdgcn_s_setprio(1);
#pragma unroll
    for (int i = 0; i < 4; i++)
#pragma unroll
      for (int j = 0; j < 2; j++) {
        acc[i + 4][j] = __builtin_amdgcn_mfma_f32_16x16x32_bf16(aHh[i], bLh[j], acc[i + 4][j], 0, 0, 0);
        acc[i + 4][j] = __builtin_amdgcn_mfma_f32_16x16x32_bf16(aHh[i], bLv[j], acc[i + 4][j], 0, 0, 0);
        acc[i + 4][j] = __builtin_amdgcn_mfma_f32_16x16x32_bf16(aHv[i], bLh[j], acc[i + 4][j], 0, 0, 0);
      }
    __builtin_amdgcn_s_setprio(0);

    // ---- hand-off: all reads of cur drained; overwrite cur; expose nxt
    asm volatile("s_waitcnt lgkmcnt(0)" ::: "memory");
    __builtin_amdgcn_s_barrier();              // all waves done reading cur
    asm volatile("" ::: "memory");
    {
      int kn = (t + 2 < nk) ? ((t + 2) << 5) : 0;   // tail: dead re-stage
      STG(t & 1, kn);
    }
    asm volatile("s_waitcnt vmcnt(8)" ::: "memory"); // nxt buffer's loads landed
    __builtin_amdgcn_s_barrier();              // nxt staged visible block-wide
    asm volatile("" ::: "memory");

    // ---- boundary reads (nxt aL,bL) overlap the HH MFMA cluster
#pragma unroll
    for (int i = 0; i < 4; i++) {
      aLh[i] = *(const bf16x8*)(na + i * 512);
      aLv[i] = *(const bf16x8*)(na + 8192 + i * 512);
    }
#pragma unroll
    for (int j = 0; j < 2; j++) {
      bLh[j] = *(const bf16x8*)(nb + j * 512);
      bLv[j] = *(const bf16x8*)(nb + 8192 + j * 512);
    }
    // ---- HH: MFMA acc[i4-7][j2-3] (aH x bH)
    __builtin_amdgcn_s_setprio(1);
#pragma unroll
    for (int i = 0; i < 4; i++)
#pragma unroll
      for (int j = 0; j < 2; j++) {
        acc[i + 4][j + 2] = __builtin_amdgcn_mfma_f32_16x16x32_bf16(aHh[i], bHh[j], acc[i + 4][j + 2], 0, 0, 0);
        acc[i + 4][j + 2] = __builtin_amdgcn_mfma_f32_16x16x32_bf16(aHh[i], bHv[j], acc[i + 4][j + 2], 0, 0, 0);
        acc[i + 4][j + 2] = __builtin_amdgcn_mfma_f32_16x16x32_bf16(aHv[i], bHh[j], acc[i + 4][j + 2], 0, 0, 0);
      }
    __builtin_amdgcn_s_setprio(0);
  }
#undef STG

  asm volatile("s_waitcnt vmcnt(0)" ::: "memory");   // drain tail stages
  __builtin_amdgcn_s_barrier();

  // ---- epilogue: fp32 + bias
#pragma unroll
  for (int i = 0; i < 8; i++) {
    int row0 = m0 + wr * 128 + i * 16 + quad * 4;
#pragma unroll
    for (int j = 0; j < 4; j++) {
      int col = n0 + wc * 64 + j * 16 + l15;
      float bv = bias[col];
#pragma unroll
      for (int r = 0; r < 4; r++)
        C[(size_t)(row0 + r) * N + col] = acc[i][j][r] + bv;
    }
  }
}

// ------------------------------------------- K/V conversion -> tiled planes
// 32x32 A-fragment layouts (for k_attn's swapped MFMAs):
//  K plane chunk [tile26][c6*64 + hi*32 + key32][8]: K[key][d = c*16 + hi*8 + j]
//  V plane chunk [tile26][(dc*2+kc)*64 + hi*32 + d31][8]:
//                V[key = kc*16 + hi*8 + j][d = dc*32 + d31]
// trunc 2-plane bf16, pads zeroed. Grid: 13 (64-key chunks) x 64 bh.
__global__ __launch_bounds__(256) void k_convkv(const float* __restrict__ qkv,
                                                u16* __restrict__ Kthi,
                                                u16* __restrict__ Ktlo,
                                                u16* __restrict__ Vthi,
                                                u16* __restrict__ VtloA,
                                                u16* __restrict__ VtloB) {
  int ck = blockIdx.x >> 6;        // 0..12
  int bh = blockIdx.x & 63;
  int b = bh >> 3, h = bh & 7;
  int kt = ck << 6;
  int ve  = kt < 64 ? 50 : kt < 448 ? 439 : 823;   // valid end (padded coords)
  int off = kt < 64 ? 0  : kt < 448 ? 14  : 23;    // key' - off = real n
  __shared__ float Ls[96 * 68];
  int tid = threadIdx.x;
  size_t base = (size_t)b * NTOK;
  u16* vtlo = (bh < 32) ? (VtloA + (size_t)bh * BHSTR)
                        : (VtloB + (size_t)(bh - 32) * BHSTR);
  u16* kthi = Kthi + (size_t)bh * BHSTR;
  u16* ktlo = Ktlo + (size_t)bh * BHSTR;
  u16* vthi = Vthi + (size_t)bh * BHSTR;

  // ---- K: fragment-order convert (source-coalesced; output remapped)
#pragma unroll
  for (int i = 0; i < 3; i++) {
    int c = i * 256 + tid;            // 768 = 64 keys x 12 d-chunks
    int key = c / 12, dc8 = c - key * 12;   // dc8: 8-float d-chunk 0..11
    int kp = kt + key;
    uint4 hi4 = make_uint4(0, 0, 0, 0), lo4 = make_uint4(0, 0, 0, 0);
    if (kp < ve) {
      const float* p = qkv + (base + kp - off) * QKVD + DIM + h * HD + dc8 * 8;
      float4 a = *(const float4*)p;
      float4 e = *(const float4*)(p + 4);
      float xs[8] = {a.x, a.y, a.z, a.w, e.x, e.y, e.z, e.w};
      u32 hp[4], lp[4];
#pragma unroll
      for (int j = 0; j < 4; j++) {
        u32 b0 = asu(xs[2 * j]), b1 = asu(xs[2 * j + 1]);
        hp[j] = (b0 >> 16) | (b1 & 0xffff0000u);
        float l0 = xs[2 * j] - asf(b0 & 0xffff0000u);
        float l1 = xs[2 * j + 1] - asf(b1 & 0xffff0000u);
        lp[j] = (asu(l0) >> 16) | (asu(l1) & 0xffff0000u);
      }
      hi4 = make_uint4(hp[0], hp[1], hp[2], hp[3]);
      lo4 = make_uint4(lp[0], lp[1], lp[2], lp[3]);
    }
    int tile = (kt >> 5) + (key >> 5), key32 = key & 31;
    // d = dc8*8 -> chunk c6 = dc8>>1, half hi = dc8&1; lane = hi*32 + key32
    int oc = ((dc8 >> 1) << 6) + ((dc8 & 1) << 5) + key32;
    size_t go = ((size_t)tile * 384 + oc) * 8;
    *(uint4*)(kthi + go) = hi4;
    *(uint4*)(ktlo + go) = lo4;
  }

  // ---- V: transpose via LDS, fragment-order emit (V^T A-frag layout)
#pragma unroll
  for (int i = 0; i < 6; i++) {
    int c = i * 256 + tid;            // 1536 = 64 keys x 24 float4-chunks
    int key = c / 24, fc = c - key * 24;
    int kp = kt + key;
    float4 v = make_float4(0.f, 0.f, 0.f, 0.f);
    if (kp < ve)
      v = *(const float4*)(qkv + (base + kp - off) * QKVD + 2 * DIM + h * HD + fc * 4);
    Ls[(fc * 4 + 0) * 68 + key] = v.x;
    Ls[(fc * 4 + 1) * 68 + key] = v.y;
    Ls[(fc * 4 + 2) * 68 + key] = v.z;
    Ls[(fc * 4 + 3) * 68 + key] = v.w;
  }
  __syncthreads();
#pragma unroll
  for (int i = 0; i < 3; i++) {
    int c = i * 256 + tid;            // 768 = 2 tiles x 384 chunks
    int tl = c / 384, cc = c - tl * 384;
    int dckc = cc >> 6, l = cc & 63;
    int dc = dckc >> 1, kc = dckc & 1;
    int hi = l >> 5, d31 = l & 31;
    int d = dc * 32 + d31;
    const float* ls = &Ls[d * 68 + tl * 32 + kc * 16 + hi * 8];
    u32 hp[4], lp[4];
#pragma unroll
    for (int j = 0; j < 4; j++) {
      float x0v = ls[2 * j], x1v = ls[2 * j + 1];
      u32 b0 = asu(x0v), b1 = asu(x1v);
      hp[j] = (b0 >> 16) | (b1 & 0xffff0000u);
      float l0 = x0v - asf(b0 & 0xffff0000u);
      float l1 = x1v - asf(b1 & 0xffff0000u);
      lp[j] = (asu(l0) >> 16) | (asu(l1) & 0xffff0000u);
    }
    size_t go = ((size_t)((kt >> 5) + tl) * 384 + cc) * 8;
    *(uint4*)(vthi + go) = make_uint4(hp[0], hp[1], hp[2], hp[3]);
    *(uint4*)(vtlo + go) = make_uint4(lp[0], lp[1], lp[2], lp[3]);
  }
}

// ------------------------------------------- MFMA flash attention (r6 shape)
// 7 q-tiles x 64 bh. 128 q-rows/block, 4 waves x 32 rows (q = lane&31).
// Swapped 32x32x16 MFMAs: S = mfma32(K, Q) -> lane owns one full q-row;
// row max/sum = in-register tree + one shfl_xor(32).  P -> PV B-operand via
// trunc-pack + v_permlane32_swap (pure VALU, zero LDS).  PV: O^T =
// mfma32(V^T, P) -> O in the q=lane&31 domain, stats apply directly.
// Double-buffered K/V staging, prefetch after all LDS reads, 1 barrier/tile.
__global__ __launch_bounds__(256, 2) void k_attn(const float* __restrict__ qkv,
                                              const u16* __restrict__ Kthi,
                                              const u16* __restrict__ Ktlo,
                                              const u16* __restrict__ Vthi,
                                              const u16* __restrict__ VtloA,
                                              const u16* __restrict__ VtloB,
                                              u16* __restrict__ ohi,
                                              u16* __restrict__ olo,
                                              int intra) {
  int t  = blockIdx.x >> 6;        // 0..6
  int bh = blockIdx.x & 63;
  int b = bh >> 3, h = bh & 7;

  int seg, q0, qlen;
  if (t == 0)      { seg = 0; q0 = 0;                    qlen = 50; }
  else if (t <= 3) { seg = 1; q0 = 50 + ((t - 1) << 7);  qlen = (425 - q0 < 128) ? (425 - q0) : 128; }
  else             { seg = 2; q0 = 425 + ((t - 4) << 7); qlen = (800 - q0 < 128) ? (800 - q0) : 128; }

  // key ranges in padded coords
  int r0s, r0e, r1s = 0, r1e = 0;
  if (intra) {
    r0s = (seg == 0) ? 0 : (seg == 1) ? 64 : 448;
    r0e = (seg == 0) ? 64 : (seg == 1) ? 448 : 832;
  } else {
    if (seg == 0)      { r0s = 64; r0e = 832; }
    else if (seg == 1) { r0s = 0;  r0e = 64;  r1s = 448; r1e = 832; }
    else               { r0s = 0;  r0e = 448; }
  }
  int n0t = (r0e - r0s) >> 5, n1t = (r1e - r1s) >> 5, nkt = n0t + n1t;

  __shared__ __align__(16) u16 sKV[2 * 12288];  // 2 x (Khi|Klo|Vhi|Vlo) 48KB

  int tid = threadIdx.x;
  int w = tid >> 6, lane = tid & 63, l31 = lane & 31, hi = lane >> 5;
  size_t base = (size_t)b * NTOK;
  const float sm0 = 0.10206207261596575f;   // 96^-0.5

  // staging source/dest precompute (loop-invariant per thread)
  const u16* sp0 = Kthi + (size_t)bh * BHSTR;
  const u16* sp1 = Ktlo + (size_t)bh * BHSTR;
  const u16* sp2 = Vthi + (size_t)bh * BHSTR;
  const u16* sp3 = (bh < 32) ? (VtloA + (size_t)bh * BHSTR)
                             : (VtloB + (size_t)(bh - 32) * BHSTR);
  const u16* sptr[6];
  u16* dptr[6];
#pragma unroll
  for (int j = 0; j < 6; j++) {
    int c = j * 256 + tid;           // 0..1535
    int rg = c / 384, cc = c - rg * 384;
    const u16* pb = rg == 0 ? sp0 : rg == 1 ? sp1 : rg == 2 ? sp2 : sp3;
    sptr[j] = pb + cc * 8;
    dptr[j] = &sKV[c * 8];
  }

  // ---- Q fragments (RNE 2-plane, pre-scaled): B-operand of mfma32
  //      lane holds Q[q = q0 + w*32 + l31][d = c*16 + hi*8 + j]
  bf16x8 qh[6], ql[6];
  {
    int q = q0 + w * 32 + l31; if (q > 799) q = 799;
    const float* qp = qkv + (base + q) * QKVD + h * HD;
#pragma unroll
    for (int c = 0; c < 6; c++) {
      float4 x0v = *(const float4*)(qp + c * 16 + hi * 8);
      float4 x1v = *(const float4*)(qp + c * 16 + hi * 8 + 4);
      float xs[8] = {x0v.x, x0v.y, x0v.z, x0v.w, x1v.x, x1v.y, x1v.z, x1v.w};
#pragma unroll
      for (int j = 0; j < 8; j++) {
        float x = xs[j] * sm0;
        u16 hu = f2bf(x);
        u16 lu = f2bf(x - bf2f(hu));
        qh[c][j] = (short)hu; ql[c][j] = (short)lu;
      }
    }
  }

  f32x16 oacc[3];
#pragma unroll
  for (int dc = 0; dc < 3; dc++)
#pragma unroll
    for (int r = 0; r < 16; r++) oacc[dc][r] = 0.f;
  float m_i = -1e30f, l_i = 0.f;
  int hi4 = hi << 2;                 // 4*hi for key mapping

  // ---- prologue: stage tile 0 into buf 0; barrier drains vmcnt
  {
    size_t toff = (size_t)(r0s >> 5) * 3072;
#pragma unroll
    for (int j = 0; j < 6; j++) async16(sptr[j] + toff, dptr[j]);
  }
  __syncthreads();                   // buf0 staged & visible

  for (int it = 0; it < nkt; it++) {
    int kt = (it < n0t) ? (r0s + (it << 5)) : (r1s + ((it - n0t) << 5));
    int ve = kt < 64 ? 50 : kt < 448 ? 439 : 823;
    int cur = it & 1;
    int cbo = cur * 12288;           // current buffer u16 offset

    // ---- S = K Q^T (swapped): lane gets S[key(reg,hi)][q=l31]
    f32x16 S;
#pragma unroll
    for (int r = 0; r < 16; r++) S[r] = 0.f;
#pragma unroll
    for (int c = 0; c < 6; c++) {
      const u16* kb = &sKV[cbo + (c * 64 + lane) * 8];
      bf16x8 kh = *(const bf16x8*)kb;
      bf16x8 kl = *(const bf16x8*)(kb + 3072);
      S = __builtin_amdgcn_mfma_f32_32x32x16_bf16(kh, qh[c], S, 0, 0, 0);
      S = __builtin_amdgcn_mfma_f32_32x32x16_bf16(kh, ql[c], S, 0, 0, 0);
      S = __builtin_amdgcn_mfma_f32_32x32x16_bf16(kl, qh[c], S, 0, 0, 0);
    }
    // ---- mask: key(reg,hi) = kt + (r&3) + 8*(r>>2) + 4*hi
#pragma unroll
    for (int r = 0; r < 16; r++) {
      int keyv = kt + (r & 3) + ((r >> 2) << 3) + hi4;
      S[r] = (keyv >= ve) ? -1e30f : S[r];
    }

    // ---- row stats: in-register tree + one cross-half shuffle
    float mx;
    {
      float a0 = fmaxf(fmaxf(S[0], S[1]), fmaxf(S[2], S[3]));
      float a1 = fmaxf(fmaxf(S[4], S[5]), fmaxf(S[6], S[7]));
      float a2 = fmaxf(fmaxf(S[8], S[9]), fmaxf(S[10], S[11]));
      float a3 = fmaxf(fmaxf(S[12], S[13]), fmaxf(S[14], S[15]));
      mx = fmaxf(fmaxf(a0, a1), fmaxf(a2, a3));
      mx = fmaxf(mx, __shfl_xor(mx, 32, 64));
    }
    float mn = fmaxf(m_i, mx);
    float al = __expf(m_i - mn);
    m_i = mn;
    float ps[16];
    float rs = 0.f;
#pragma unroll
    for (int r = 0; r < 16; r++) { ps[r] = __expf(S[r] - mn); rs += ps[r]; }
    rs += __shfl_xor(rs, 32, 64);
    l_i = l_i * al + rs;

    // ---- pack P (trunc 2-plane) into key-pairs, then permlane-swap into
    //      PV B-operand fragments: pB[kc] holds P[q=l31][kc*16 + hi*8 + j]
    u32 hp[8], lp[8];
#pragma unroll
    for (int p = 0; p < 8; p++) {
      u32 b0 = asu(ps[2 * p]), b1 = asu(ps[2 * p + 1]);
      hp[p] = (b0 >> 16) | (b1 & 0xffff0000u);
      float lo0 = ps[2 * p] - asf(b0 & 0xffff0000u);
      float lo1 = ps[2 * p + 1] - asf(b1 & 0xffff0000u);
      lp[p] = (asu(lo0) >> 16) | (asu(lo1) & 0xffff0000u);
    }
    bf16x8 pBh[2], pBl[2];
#pragma unroll
    for (int kc = 0; kc < 2; kc++) {
      u32 a0 = hp[4 * kc + 0], b0 = hp[4 * kc + 2];
      u32 a1 = hp[4 * kc + 1], b1 = hp[4 * kc + 3];
      asm volatile("v_permlane32_swap_b32 %0, %1" : "+v"(a0), "+v"(b0));
      asm volatile("v_permlane32_swap_b32 %0, %1" : "+v"(a1), "+v"(b1));
      union { u32 u[4]; bf16x8 v; } ch; ch.u[0] = a0; ch.u[1] = a1; ch.u[2] = b0; ch.u[3] = b1;
      pBh[kc] = ch.v;
      u32 c0 = lp[4 * kc + 0], d0 = lp[4 * kc + 2];
      u32 c1 = lp[4 * kc + 1], d1 = lp[4 * kc + 3];
      asm volatile("v_permlane32_swap_b32 %0, %1" : "+v"(c0), "+v"(d0));
      asm volatile("v_permlane32_swap_b32 %0, %1" : "+v"(c1), "+v"(d1));
      union { u32 u[4]; bf16x8 v; } cl; cl.u[0] = c0; cl.u[1] = c1; cl.u[2] = d0; cl.u[3] = d1;
      pBl[kc] = cl.v;
    }

    // ---- bulk V^T fragment read (last LDS reads of the current tile)
    bf16x8 vh[3][2], vl[3][2];
#pragma unroll
    for (int dc = 0; dc < 3; dc++)
#pragma unroll
      for (int kc = 0; kc < 2; kc++) {
        const u16* vb = &sKV[cbo + 6144 + ((dc * 2 + kc) * 64 + lane) * 8];
        vh[dc][kc] = *(const bf16x8*)vb;
        vl[dc][kc] = *(const bf16x8*)(vb + 3072);
      }

    // ---- stage tile it+1 into buf[cur^1] (after ALL current-tile LDS reads)
    if (it + 1 < nkt) {
      int kn = (it + 1 < n0t) ? (r0s + ((it + 1) << 5))
                              : (r1s + ((it + 1 - n0t) << 5));
      size_t toff = (size_t)(kn >> 5) * 3072;
      int nbo = (cur ^ 1) * 12288;
#pragma unroll
      for (int j = 0; j < 6; j++) async16(sptr[j] + toff, dptr[j] + nbo);
    }

    // ---- rescale O^T, then O^T += V^T P  (O in q=lane&31 domain)
#pragma unroll
    for (int dc = 0; dc < 3; dc++)
#pragma unroll
      for (int r = 0; r < 16; r++) oacc[dc][r] *= al;
#pragma unroll
    for (int dc = 0; dc < 3; dc++)
#pragma unroll
      for (int kc = 0; kc < 2; kc++) {
        oacc[dc] = __builtin_amdgcn_mfma_f32_32x32x16_bf16(vh[dc][kc], pBh[kc], oacc[dc], 0, 0, 0);
        oacc[dc] = __builtin_amdgcn_mfma_f32_32x32x16_bf16(vl[dc][kc], pBh[kc], oacc[dc], 0, 0, 0);
        oacc[dc] = __builtin_amdgcn_mfma_f32_32x32x16_bf16(vh[dc][kc], pBl[kc], oacc[dc], 0, 0, 0);
      }

    // ---- single barrier: seals reads of buf[cur] and drains the prefetch
    __syncthreads();
  }

  // ---- epilogue: RNE 2-plane A-operand output (O^T: d in regs, q = l31)
  float inv = 1.0f / l_i;
  int rl = w * 32 + l31;
  if (rl < qlen) {
    size_t rowb = (base + q0 + rl) * DIM + h * HD;
#pragma unroll
    for (int dc = 0; dc < 3; dc++)
#pragma unroll
      for (int r = 0; r < 16; r++) {
        int d = dc * 32 + (r & 3) + ((r >> 2) << 3) + hi4;
        float v = oacc[dc][r] * inv;
        u16 hu = f2bf(v);
        ohi[rowb + d] = hu;
        olo[rowb + d] = f2bf(v - bf2f(hu));
      }
  }
}

// ---------------------------------------------------------------- layernorm
__global__ __launch_bounds__(256) void k_ln(const float* __restrict__ x,
                                            const float* __restrict__ g,
                                            const float* __restrict__ be,
                                            float* __restrict__ outp) {
  int row = blockIdx.x;
  const float* xr = x + (size_t)row * DIM;
  float v[3]; float s = 0.f;
#pragma unroll
  for (int i = 0; i < 3; i++) { v[i] = xr[threadIdx.x + (i << 8)]; s += v[i]; }
#pragma unroll
  for (int off = 1; off < 64; off <<= 1) s += __shfl_xor(s, off, 64);
  __shared__ float red[4];
  int wv = threadIdx.x >> 6;
  if ((threadIdx.x & 63) == 0) red[wv] = s;
  __syncthreads();
  float mu = (red[0] + red[1] + red[2] + red[3]) * (1.0f / 768.0f);
  float sq = 0.f;
#pragma unroll
  for (int i = 0; i < 3; i++) { float d2 = v[i] - mu; sq += d2 * d2; }
#pragma unroll
  for (int off = 1; off < 64; off <<= 1) sq += __shfl_xor(sq, off, 64);
  __syncthreads();
  if ((threadIdx.x & 63) == 0) red[wv] = sq;
  __syncthreads();
  float var = (red[0] + red[1] + red[2] + red[3]) * (1.0f / 768.0f);
  float rstd = rsqrtf(var + 1e-5f);
  float* orow = outp + (size_t)row * DIM;
#pragma unroll
  for (int i = 0; i < 3; i++) {
    int d = threadIdx.x + (i << 8);
    orow[d] = (v[i] - mu) * rstd * g[d] + be[d];
  }
}

// ---------------------------------------------------------------- launch
extern "C" void kernel_launch(void* const* d_in, const int* in_sizes, int n_in,
                              void* d_out, int out_size, void* d_ws, size_t ws_size,
                              hipStream_t stream) {
  (void)in_sizes; (void)n_in; (void)out_size; (void)ws_size;
  const float* seq0 = (const float*)d_in[0];
  const float* seq1 = (const float*)d_in[1];
  const float* seq2 = (const float*)d_in[2];

  const size_t NX   = (size_t)ROWS * DIM;    // 4,915,200
  const size_t NQKV = (size_t)ROWS * QKVD;   // 14,745,600
  const int WIN_N   = QKVD * DIM;            // 1,769,472
  const int WOUT_N  = DIM * DIM;             //   589,824
  const size_t PLN  = (size_t)64 * BHSTR;    // 5,111,808 u16 per plane

  // ws (128.19 MiB): x0 | qkv | att | X | S.  Time-shared overlays per layer.
  float* x0   = (float*)d_ws;
  float* qkvb = x0   + NX;
  float* att  = qkvb + NQKV;
  float* X    = att  + NX;
  u16*   S    = (u16*)(X + NX);
  u16*   WPh  = S;            u16* WPl  = S + WIN_N;
  u16*   Vthi = S;
  u16*   P1h  = (u16*)x0;     u16* P1l  = P1h + NX;
  u16*   P2h  = (u16*)att;    u16* P2l  = P2h + NX;
  u16*   Kthi = (u16*)x0;     u16* VtloA = Kthi + PLN;   // 32 bh
  u16*   Ktlo = (u16*)X;      u16* VtloB = Ktlo + PLN;   // 32 bh

  for (int g = 0; g < 2; g++) {           // g=0: inter, g=1: intra
    const float* w_in  = (const float*)d_in[3 + 6 * g];
    const float* b_in  = (const float*)d_in[4 + 6 * g];
    const float* w_out = (const float*)d_in[5 + 6 * g];
    const float* b_out = (const float*)d_in[6 + 6 * g];
    const float* ln_g  = (const float*)d_in[7 + 6 * g];
    const float* ln_b  = (const float*)d_in[8 + 6 * g];

    k_embed<<<ROWS, 256, 0, stream>>>(seq0, seq1, seq2, att);

    for (int l = 0; l < 4; l++) {
      if (l == 0)
        k_conv<<<(int)(NX / 8 / 256), 256, 0, stream>>>(att, P1h, P1l, (int)(NX / 8));
      k_conv<<<WIN_N / 8 / 256, 256, 0, stream>>>(
          w_in + (size_t)l * WIN_N, WPh, WPl, WIN_N / 8);
      k_gemm_qkv<<<dim3(QKVD / 256, ROWS / 256), 512, 0, stream>>>(
          P1h, P1l, WPh, WPl, b_in + (size_t)l * QKVD, qkvb, QKVD, DIM);

      k_convkv<<<13 * 64, 256, 0, stream>>>(qkvb, Kthi, Ktlo, Vthi, VtloA, VtloB);
      k_attn<<<7 * 64, 256, 0, stream>>>(qkvb, Kthi, Ktlo, Vthi, VtloA, VtloB,
                                         P2h, P2l, g);

      k_conv<<<WOUT_N / 8 / 256, 256, 0, stream>>>(
          w_out + (size_t)l * WOUT_N, WPh, WPl, WOUT_N / 8);
      k_gemm_out<<<dim3(DIM / 128, ROWS / 128), 256, 0, stream>>>(
          P2h, P2l, WPh, WPl, b_out + (size_t)l * DIM, X,
          P1h, P1l, (l == 3) ? 1 : 0, DIM, DIM);
    }
    k_ln<<<ROWS, 256, 0, stream>>>(X, ln_g, ln_b,
                                   (float*)d_out + (size_t)g * ROWS * DIM);
  }
}